// Round 1
// baseline (923.849 us; speedup 1.0000x reference)
//
#include <hip/hip_runtime.h>
#include <hip/hip_bf16.h>
#include <math.h>

#define H 128
#define RBF 50
#define CUTF 5.0f

// ---------------------------------------------------------------------------
// x[n][h] = emb[atom_types[n]][h]
__global__ __launch_bounds__(256) void init_x_kernel(
    const int* __restrict__ atype, const float* __restrict__ emb,
    float* __restrict__ x, int Nn)
{
    int idx = blockIdx.x * blockDim.x + threadIdx.x;       // one float4 per thread
    if (idx * 4 >= Nn * H) return;
    int n = idx >> 5;                  // 32 float4 per row (128 floats)
    int c = (idx & 31) * 4;
    const float4 v = *(const float4*)(emb + atype[n] * H + c);
    *(float4*)(x + n * H + c) = v;
}

// ---------------------------------------------------------------------------
// Compact edges with d < CUT (Cenv==0 otherwise -> exact skip)
__global__ __launch_bounds__(256) void edge_prep_kernel(
    const float* __restrict__ pos, const int* __restrict__ ei, int E,
    int* __restrict__ cnt, int* __restrict__ asrc, int* __restrict__ adst,
    float* __restrict__ ad)
{
    int e = blockIdx.x * blockDim.x + threadIdx.x;
    if (e >= E) return;
    int s = ei[e], t = ei[E + e];
    float dx = pos[3 * s]     - pos[3 * t];
    float dy = pos[3 * s + 1] - pos[3 * t + 1];
    float dz = pos[3 * s + 2] - pos[3 * t + 2];
    float d = sqrtf(dx * dx + dy * dy + dz * dz + 1e-12f);
    if (d < CUTF) {
        int slot = atomicAdd(cnt, 1);
        asrc[slot] = s; adst[slot] = t; ad[slot] = d;
    }
}

// ---------------------------------------------------------------------------
// One wave (64 lanes) per active edge. lane handles channels h0=lane, h1=lane+64.
//   t = tanh(rbf @ fw1 + fb1); W = (t @ fw2 + fb2) * Cenv
//   msg = h[src]*W ; atomicAdd into agg[dst]
__global__ __launch_bounds__(256) void edge_filter_kernel(
    const int* __restrict__ cnt,
    const int* __restrict__ asrc, const int* __restrict__ adst,
    const float* __restrict__ ad,
    const float* __restrict__ fw1, const float* __restrict__ fb1,
    const float* __restrict__ fw2, const float* __restrict__ fb2,
    const float* __restrict__ hbuf, float* __restrict__ agg)
{
    const int lane = threadIdx.x & 63;
    const int wid = (blockIdx.x * blockDim.x + threadIdx.x) >> 6;
    const int nw  = (gridDim.x * blockDim.x) >> 6;
    const int count = *cnt;
    const float step  = CUTF / 49.0f;
    const float coeff = -0.5f / (step * step);
    const int h0 = lane, h1 = lane + 64;
    const float b1_0 = fb1[h0], b1_1 = fb1[h1];
    const float b2_0 = fb2[h0], b2_1 = fb2[h1];

    for (int i = wid; i < count; i += nw) {
        int s = asrc[i], t = adst[i];
        float d = ad[i];
        float cenv = 0.5f * (cosf(d * (3.14159265358979323846f / CUTF)) + 1.0f);

        // GEMV1: t = tanh(rbf @ fw1 + fb1)  (rbf recomputed per lane, stays in regs)
        float t0 = b1_0, t1 = b1_1;
        #pragma unroll
        for (int r = 0; r < RBF; ++r) {
            float u = d - (float)r * step;
            float rb = expf(coeff * u * u);
            t0 = fmaf(rb, fw1[r * H + h0], t0);
            t1 = fmaf(rb, fw1[r * H + h1], t1);
        }
        t0 = tanhf(t0); t1 = tanhf(t1);

        // GEMV2: W = t @ fw2 + fb2 via shuffle broadcast of t across the wave
        float w0 = b2_0, w1v = b2_1;
        #pragma unroll 8
        for (int k = 0; k < 64; ++k) {
            float bb = __shfl(t0, k, 64);
            w0  = fmaf(bb, fw2[k * H + h0], w0);
            w1v = fmaf(bb, fw2[k * H + h1], w1v);
        }
        #pragma unroll 8
        for (int k = 0; k < 64; ++k) {
            float bb = __shfl(t1, k, 64);
            w0  = fmaf(bb, fw2[(64 + k) * H + h0], w0);
            w1v = fmaf(bb, fw2[(64 + k) * H + h1], w1v);
        }
        w0 *= cenv; w1v *= cenv;

        float m0 = hbuf[s * H + h0] * w0;
        float m1 = hbuf[s * H + h1] * w1v;
        atomicAdd(&agg[t * H + h0], m0);
        atomicAdd(&agg[t * H + h1], m1);
    }
}

// ---------------------------------------------------------------------------
// C[M,128] = A[M,128] @ W[128,128] (+bias) (tanh?) (+resid)
// BM=64, BK=32, 256 threads, microtile 4 rows x (4+4) cols.
__global__ __launch_bounds__(256) void gemm128_kernel(
    const float* __restrict__ A, const float* __restrict__ W,
    const float* __restrict__ bias, const float* __restrict__ resid,
    float* __restrict__ C, int M, int act_tanh)
{
    __shared__ float As[64][33];    // padded to kill bank conflicts
    __shared__ float Ws[32][128];

    const int tid = threadIdx.x;
    const int m0 = blockIdx.x * 64;
    const int r0 = (tid >> 4) * 4;         // 0..60
    const int c0 = (tid & 15) * 4;         // 0..60 ; cols {c0..c0+3, c0+64..c0+67}

    float acc[4][8];
    #pragma unroll
    for (int j = 0; j < 4; ++j)
        #pragma unroll
        for (int c = 0; c < 8; ++c) acc[j][c] = 0.0f;

    for (int kc = 0; kc < 128; kc += 32) {
        // stage A chunk (64 x 32)
        {
            int r = tid >> 3;              // 0..31
            int kk = (tid & 7) * 4;
            #pragma unroll
            for (int p = 0; p < 2; ++p) {
                int row = r + p * 32;
                float4 v = make_float4(0.f, 0.f, 0.f, 0.f);
                if (m0 + row < M) v = *(const float4*)(A + (size_t)(m0 + row) * H + kc + kk);
                As[row][kk] = v.x; As[row][kk + 1] = v.y;
                As[row][kk + 2] = v.z; As[row][kk + 3] = v.w;
            }
        }
        // stage W chunk (32 x 128)
        {
            int wr = tid >> 5;             // 0..7
            int wc = (tid & 31) * 4;
            #pragma unroll
            for (int p = 0; p < 4; ++p) {
                int row = wr + p * 8;
                *(float4*)&Ws[row][wc] = *(const float4*)(W + (size_t)(kc + row) * H + wc);
            }
        }
        __syncthreads();
        #pragma unroll
        for (int k = 0; k < 32; ++k) {
            float a_[4];
            #pragma unroll
            for (int j = 0; j < 4; ++j) a_[j] = As[r0 + j][k];
            float4 wlo = *(float4*)&Ws[k][c0];
            float4 whi = *(float4*)&Ws[k][c0 + 64];
            float w_[8] = {wlo.x, wlo.y, wlo.z, wlo.w, whi.x, whi.y, whi.z, whi.w};
            #pragma unroll
            for (int j = 0; j < 4; ++j)
                #pragma unroll
                for (int c = 0; c < 8; ++c)
                    acc[j][c] = fmaf(a_[j], w_[c], acc[j][c]);
        }
        __syncthreads();
    }

    // epilogue
    #pragma unroll
    for (int j = 0; j < 4; ++j) {
        int row = m0 + r0 + j;
        if (row >= M) continue;
        #pragma unroll
        for (int hh = 0; hh < 2; ++hh) {
            int cb = c0 + hh * 64;
            float v0 = acc[j][hh * 4 + 0], v1 = acc[j][hh * 4 + 1];
            float v2 = acc[j][hh * 4 + 2], v3 = acc[j][hh * 4 + 3];
            if (bias) {
                v0 += bias[cb]; v1 += bias[cb + 1]; v2 += bias[cb + 2]; v3 += bias[cb + 3];
            }
            if (act_tanh) {
                v0 = tanhf(v0); v1 = tanhf(v1); v2 = tanhf(v2); v3 = tanhf(v3);
            }
            if (resid) {
                const float4 rv = *(const float4*)(resid + (size_t)row * H + cb);
                v0 += rv.x; v1 += rv.y; v2 += rv.z; v3 += rv.w;
            }
            float4 out = make_float4(v0, v1, v2, v3);
            *(float4*)(C + (size_t)row * H + cb) = out;
        }
    }
}

// ---------------------------------------------------------------------------
// Output head: one wave per atom; lane c in [0,64):
//   y_c = tanh(sum_k x[n][k]*w1[k][c] + b1[c]);  e = sum_c y_c*w2[c] + b2
//   atomicAdd(energy[batch[n]], e)
__global__ __launch_bounds__(256) void out_net_kernel(
    const float* __restrict__ x, const int* __restrict__ batch,
    const float* __restrict__ w1, const float* __restrict__ b1,
    const float* __restrict__ w2, const float* __restrict__ b2,
    float* __restrict__ energy, int Nn)
{
    const int lane = threadIdx.x & 63;
    const int n = (blockIdx.x * blockDim.x + threadIdx.x) >> 6;
    if (n >= Nn) return;
    const float* xr = x + (size_t)n * H;
    float acc = b1[lane];
    #pragma unroll 8
    for (int k = 0; k < H; ++k)
        acc = fmaf(xr[k], w1[k * 64 + lane], acc);
    acc = tanhf(acc) * w2[lane];
    #pragma unroll
    for (int off = 32; off; off >>= 1)
        acc += __shfl_xor(acc, off, 64);
    if (lane == 0)
        atomicAdd(&energy[batch[n]], acc + b2[0]);
}

// ---------------------------------------------------------------------------
extern "C" void kernel_launch(void* const* d_in, const int* in_sizes, int n_in,
                              void* d_out, int out_size, void* d_ws, size_t ws_size,
                              hipStream_t stream)
{
    const int*   atype = (const int*)  d_in[0];
    const float* pos   = (const float*)d_in[1];
    const int*   ei    = (const int*)  d_in[2];
    const int*   batch = (const int*)  d_in[3];
    const float* emb   = (const float*)d_in[4];
    const float* fw1   = (const float*)d_in[5];
    const float* fb1   = (const float*)d_in[6];
    const float* fw2   = (const float*)d_in[7];
    const float* fb2   = (const float*)d_in[8];
    const float* lin1w = (const float*)d_in[9];
    const float* lin2w = (const float*)d_in[10];
    const float* lin2b = (const float*)d_in[11];
    const float* blkw  = (const float*)d_in[12];
    const float* blkb  = (const float*)d_in[13];
    const float* ow1   = (const float*)d_in[14];
    const float* ob1   = (const float*)d_in[15];
    const float* ow2   = (const float*)d_in[16];
    const float* ob2   = (const float*)d_in[17];

    const int Nn = in_sizes[0];
    const int E  = in_sizes[2] / 2;
    float* energy = (float*)d_out;

    // workspace layout
    char* w = (char*)d_ws;
    int*   cnt  = (int*)w;                              // 256 B region
    float* x    = (float*)(w + 256);                    // N*H
    float* hbuf = x + (size_t)Nn * H;                   // N*H
    float* agg  = hbuf + (size_t)Nn * H;                // N*H
    int*   asrc = (int*)(agg + (size_t)Nn * H);         // E
    int*   adst = asrc + E;                             // E
    float* ad   = (float*)(adst + E);                   // E

    hipMemsetAsync(cnt, 0, 256, stream);
    hipMemsetAsync(energy, 0, (size_t)out_size * sizeof(float), stream);

    // x = emb[atom_types]
    {
        int total = (Nn * H) / 4;
        init_x_kernel<<<(total + 255) / 256, 256, 0, stream>>>(atype, emb, x, Nn);
    }
    // edge compaction
    edge_prep_kernel<<<(E + 255) / 256, 256, 0, stream>>>(pos, ei, E, cnt, asrc, adst, ad);

    const int gemmGrid = (Nn + 63) / 64;
    for (int i = 0; i < 2; ++i) {
        const float* fw1i = fw1 + (size_t)i * RBF * H;
        const float* fb1i = fb1 + (size_t)i * H;
        const float* fw2i = fw2 + (size_t)i * H * H;
        const float* fb2i = fb2 + (size_t)i * H;
        const float* l1w  = lin1w + (size_t)i * H * H;
        const float* l2w  = lin2w + (size_t)i * H * H;
        const float* l2b  = lin2b + (size_t)i * H;
        const float* bw   = blkw + (size_t)i * H * H;
        const float* bb   = blkb + (size_t)i * H;

        // h = x @ lin1 (no bias)
        gemm128_kernel<<<gemmGrid, 256, 0, stream>>>(x, l1w, nullptr, nullptr, hbuf, Nn, 0);
        // agg = 0
        hipMemsetAsync(agg, 0, (size_t)Nn * H * sizeof(float), stream);
        // scatter messages over active edges
        edge_filter_kernel<<<1024, 256, 0, stream>>>(cnt, asrc, adst, ad,
                                                     fw1i, fb1i, fw2i, fb2i, hbuf, agg);
        // h = tanh(agg @ lin2 + b)
        gemm128_kernel<<<gemmGrid, 256, 0, stream>>>(agg, l2w, l2b, nullptr, hbuf, Nn, 1);
        // x = x + h @ blk_w + blk_b
        gemm128_kernel<<<gemmGrid, 256, 0, stream>>>(hbuf, bw, bb, x, x, Nn, 0);
    }

    // output head
    {
        int blocks = (Nn * 64 + 255) / 256;
        out_net_kernel<<<blocks, 256, 0, stream>>>(x, batch, ow1, ob1, ow2, ob2, energy, Nn);
    }
}

// Round 2
// 524.138 us; speedup vs baseline: 1.7626x; 1.7626x over previous
//
#include <hip/hip_runtime.h>
#include <hip/hip_bf16.h>
#include <math.h>

#define H 128
#define RBF 50
#define CUTF 5.0f

// ---------------------------------------------------------------------------
// x[n][h] = emb[atom_types[n]][h]
__global__ __launch_bounds__(256) void init_x_kernel(
    const int* __restrict__ atype, const float* __restrict__ emb,
    float* __restrict__ x, int Nn)
{
    int idx = blockIdx.x * blockDim.x + threadIdx.x;       // one float4 per thread
    if (idx * 4 >= Nn * H) return;
    int n = idx >> 5;                  // 32 float4 per row (128 floats)
    int c = (idx & 31) * 4;
    const float4 v = *(const float4*)(emb + atype[n] * H + c);
    *(float4*)(x + n * H + c) = v;
}

// ---------------------------------------------------------------------------
// Compact edges with d < CUT (Cenv==0 otherwise -> exact skip)
__global__ __launch_bounds__(256) void edge_prep_kernel(
    const float* __restrict__ pos, const int* __restrict__ ei, int E,
    int* __restrict__ cnt, int* __restrict__ asrc, int* __restrict__ adst,
    float* __restrict__ ad)
{
    int e = blockIdx.x * blockDim.x + threadIdx.x;
    if (e >= E) return;
    int s = ei[e], t = ei[E + e];
    float dx = pos[3 * s]     - pos[3 * t];
    float dy = pos[3 * s + 1] - pos[3 * t + 1];
    float dz = pos[3 * s + 2] - pos[3 * t + 2];
    float d = sqrtf(dx * dx + dy * dy + dz * dz + 1e-12f);
    if (d < CUTF) {
        int slot = atomicAdd(cnt, 1);
        asrc[slot] = s; adst[slot] = t; ad[slot] = d;
    }
}

// ---------------------------------------------------------------------------
// One wave (64 lanes) per active edge. lane handles channels h0=lane, h1=lane+64.
//   t = tanh(rbf @ fw1 + fb1); W = (t @ fw2 + fb2) * Cenv
//   msg = h[src]*W ; atomicAdd into agg[dst]
__global__ __launch_bounds__(256) void edge_filter_kernel(
    const int* __restrict__ cnt,
    const int* __restrict__ asrc, const int* __restrict__ adst,
    const float* __restrict__ ad,
    const float* __restrict__ fw1, const float* __restrict__ fb1,
    const float* __restrict__ fw2, const float* __restrict__ fb2,
    const float* __restrict__ hbuf, float* __restrict__ agg)
{
    const int lane = threadIdx.x & 63;
    const int wid = (blockIdx.x * blockDim.x + threadIdx.x) >> 6;
    const int nw  = (gridDim.x * blockDim.x) >> 6;
    const int count = *cnt;
    const float step  = CUTF / 49.0f;
    const float coeff = -0.5f / (step * step);
    const int h0 = lane, h1 = lane + 64;
    const float b1_0 = fb1[h0], b1_1 = fb1[h1];
    const float b2_0 = fb2[h0], b2_1 = fb2[h1];

    for (int i = wid; i < count; i += nw) {
        int s = asrc[i], t = adst[i];
        float d = ad[i];
        float cenv = 0.5f * (cosf(d * (3.14159265358979323846f / CUTF)) + 1.0f);

        // GEMV1: t = tanh(rbf @ fw1 + fb1)  (rbf recomputed per lane, stays in regs)
        float t0 = b1_0, t1 = b1_1;
        #pragma unroll
        for (int r = 0; r < RBF; ++r) {
            float u = d - (float)r * step;
            float rb = expf(coeff * u * u);
            t0 = fmaf(rb, fw1[r * H + h0], t0);
            t1 = fmaf(rb, fw1[r * H + h1], t1);
        }
        t0 = tanhf(t0); t1 = tanhf(t1);

        // GEMV2: W = t @ fw2 + fb2 via shuffle broadcast of t across the wave
        float w0 = b2_0, w1v = b2_1;
        #pragma unroll 8
        for (int k = 0; k < 64; ++k) {
            float bb = __shfl(t0, k, 64);
            w0  = fmaf(bb, fw2[k * H + h0], w0);
            w1v = fmaf(bb, fw2[k * H + h1], w1v);
        }
        #pragma unroll 8
        for (int k = 0; k < 64; ++k) {
            float bb = __shfl(t1, k, 64);
            w0  = fmaf(bb, fw2[(64 + k) * H + h0], w0);
            w1v = fmaf(bb, fw2[(64 + k) * H + h1], w1v);
        }
        w0 *= cenv; w1v *= cenv;

        float m0 = hbuf[s * H + h0] * w0;
        float m1 = hbuf[s * H + h1] * w1v;
        atomicAdd(&agg[t * H + h0], m0);
        atomicAdd(&agg[t * H + h1], m1);
    }
}

// ---------------------------------------------------------------------------
// C[M,128] = A[M,128] @ W[128,128] (+bias) (tanh?) (+resid)
// BM=64, BK=32, 256 threads, microtile 4 rows x (4+4) cols.
__global__ __launch_bounds__(256) void gemm128_kernel(
    const float* __restrict__ A, const float* __restrict__ W,
    const float* __restrict__ bias, const float* __restrict__ resid,
    float* __restrict__ C, int M, int act_tanh)
{
    __shared__ float As[64][33];    // padded to kill bank conflicts
    __shared__ float Ws[32][128];

    const int tid = threadIdx.x;
    const int m0 = blockIdx.x * 64;
    const int r0 = (tid >> 4) * 4;         // 0..60
    const int c0 = (tid & 15) * 4;         // 0..60 ; cols {c0..c0+3, c0+64..c0+67}

    float acc[4][8];
    #pragma unroll
    for (int j = 0; j < 4; ++j)
        #pragma unroll
        for (int c = 0; c < 8; ++c) acc[j][c] = 0.0f;

    for (int kc = 0; kc < 128; kc += 32) {
        // stage A chunk (64 x 32)
        {
            int r = tid >> 3;              // 0..31
            int kk = (tid & 7) * 4;
            #pragma unroll
            for (int p = 0; p < 2; ++p) {
                int row = r + p * 32;
                float4 v = make_float4(0.f, 0.f, 0.f, 0.f);
                if (m0 + row < M) v = *(const float4*)(A + (size_t)(m0 + row) * H + kc + kk);
                As[row][kk] = v.x; As[row][kk + 1] = v.y;
                As[row][kk + 2] = v.z; As[row][kk + 3] = v.w;
            }
        }
        // stage W chunk (32 x 128)
        {
            int wr = tid >> 5;             // 0..7
            int wc = (tid & 31) * 4;
            #pragma unroll
            for (int p = 0; p < 4; ++p) {
                int row = wr + p * 8;
                *(float4*)&Ws[row][wc] = *(const float4*)(W + (size_t)(kc + row) * H + wc);
            }
        }
        __syncthreads();
        #pragma unroll
        for (int k = 0; k < 32; ++k) {
            float a_[4];
            #pragma unroll
            for (int j = 0; j < 4; ++j) a_[j] = As[r0 + j][k];
            float4 wlo = *(float4*)&Ws[k][c0];
            float4 whi = *(float4*)&Ws[k][c0 + 64];
            float w_[8] = {wlo.x, wlo.y, wlo.z, wlo.w, whi.x, whi.y, whi.z, whi.w};
            #pragma unroll
            for (int j = 0; j < 4; ++j)
                #pragma unroll
                for (int c = 0; c < 8; ++c)
                    acc[j][c] = fmaf(a_[j], w_[c], acc[j][c]);
        }
        __syncthreads();
    }

    // epilogue
    #pragma unroll
    for (int j = 0; j < 4; ++j) {
        int row = m0 + r0 + j;
        if (row >= M) continue;
        #pragma unroll
        for (int hh = 0; hh < 2; ++hh) {
            int cb = c0 + hh * 64;
            float v0 = acc[j][hh * 4 + 0], v1 = acc[j][hh * 4 + 1];
            float v2 = acc[j][hh * 4 + 2], v3 = acc[j][hh * 4 + 3];
            if (bias) {
                v0 += bias[cb]; v1 += bias[cb + 1]; v2 += bias[cb + 2]; v3 += bias[cb + 3];
            }
            if (act_tanh) {
                v0 = tanhf(v0); v1 = tanhf(v1); v2 = tanhf(v2); v3 = tanhf(v3);
            }
            if (resid) {
                const float4 rv = *(const float4*)(resid + (size_t)row * H + cb);
                v0 += rv.x; v1 += rv.y; v2 += rv.z; v3 += rv.w;
            }
            float4 out = make_float4(v0, v1, v2, v3);
            *(float4*)(C + (size_t)row * H + cb) = out;
        }
    }
}

// ---------------------------------------------------------------------------
// Output head, GEMM-tiled + fused energy reduction.
// Block: 256 threads, tile = 64 atoms x 64 cols.
//   y = tanh(x_tile @ w1 + b1)            (w1: [128][64] row-major, LDS-staged)
//   e[atom] = y_row . w2 + b2             (16-lane shuffle reduce)
//   segmented flush: batch sorted -> ~1-2 atomics per block.
__global__ __launch_bounds__(256) void out_head_kernel(
    const float* __restrict__ x, const int* __restrict__ batch,
    const float* __restrict__ w1, const float* __restrict__ b1,
    const float* __restrict__ w2, const float* __restrict__ b2,
    float* __restrict__ energy, int Nn)
{
    __shared__ float As[64][33];
    __shared__ float Ws[32][68];
    __shared__ float e_lds[64];
    __shared__ int   gid_lds[64];

    const int tid = threadIdx.x;
    const int m0 = blockIdx.x * 64;
    const int r0 = (tid >> 4) * 4;         // 0..60
    const int c0 = (tid & 15) * 4;         // 0..60

    float acc[4][4];
    #pragma unroll
    for (int j = 0; j < 4; ++j)
        #pragma unroll
        for (int c = 0; c < 4; ++c) acc[j][c] = 0.0f;

    for (int kc = 0; kc < 128; kc += 32) {
        // stage x chunk (64 rows x 32 k)
        {
            int r = tid >> 3;              // 0..31
            int kk = (tid & 7) * 4;
            #pragma unroll
            for (int p = 0; p < 2; ++p) {
                int row = r + p * 32;
                float4 v = make_float4(0.f, 0.f, 0.f, 0.f);
                if (m0 + row < Nn) v = *(const float4*)(x + (size_t)(m0 + row) * H + kc + kk);
                As[row][kk] = v.x; As[row][kk + 1] = v.y;
                As[row][kk + 2] = v.z; As[row][kk + 3] = v.w;
            }
        }
        // stage w1 chunk (32 k x 64 cols)
        {
            int wr = tid >> 4;             // 0..15
            int wc = (tid & 15) * 4;       // 0..60
            #pragma unroll
            for (int p = 0; p < 2; ++p) {
                int row = wr + p * 16;
                *(float4*)&Ws[row][wc] = *(const float4*)(w1 + (size_t)(kc + row) * 64 + wc);
            }
        }
        __syncthreads();
        #pragma unroll
        for (int k = 0; k < 32; ++k) {
            float a_[4];
            #pragma unroll
            for (int j = 0; j < 4; ++j) a_[j] = As[r0 + j][k];
            float4 wv = *(float4*)&Ws[k][c0];
            float w_[4] = {wv.x, wv.y, wv.z, wv.w};
            #pragma unroll
            for (int j = 0; j < 4; ++j)
                #pragma unroll
                for (int c = 0; c < 4; ++c)
                    acc[j][c] = fmaf(a_[j], w_[c], acc[j][c]);
        }
        __syncthreads();
    }

    // epilogue: e_partial[j] = sum_c tanh(acc+b1)*w2  over this thread's 4 cols
    const float4 b1v = *(const float4*)(b1 + c0);
    const float4 w2v = *(const float4*)(w2 + c0);
    float ep[4];
    #pragma unroll
    for (int j = 0; j < 4; ++j) {
        float v0 = tanhf(acc[j][0] + b1v.x);
        float v1 = tanhf(acc[j][1] + b1v.y);
        float v2 = tanhf(acc[j][2] + b1v.z);
        float v3 = tanhf(acc[j][3] + b1v.w);
        ep[j] = v0 * w2v.x + v1 * w2v.y + v2 * w2v.z + v3 * w2v.w;
    }
    // reduce across the 16 col-group lanes (same row set shares 16 consecutive lanes)
    #pragma unroll
    for (int off = 1; off < 16; off <<= 1) {
        #pragma unroll
        for (int j = 0; j < 4; ++j) ep[j] += __shfl_xor(ep[j], off, 64);
    }
    if ((tid & 15) == 0) {
        const float b2v = b2[0];
        #pragma unroll
        for (int j = 0; j < 4; ++j) {
            int row = r0 + j;
            e_lds[row] = ep[j] + b2v;
        }
    }
    // stage batch ids (coalesced, by wave 0)
    if (tid < 64) {
        int row = m0 + tid;
        gid_lds[tid] = (row < Nn) ? batch[row] : -1;
    }
    __syncthreads();

    // segmented flush by thread 0 (batch sorted: ~1-2 distinct gids per block)
    if (tid == 0) {
        int cur = -1; float sum = 0.0f;
        for (int r = 0; r < 64; ++r) {
            int g = gid_lds[r];
            if (g < 0) continue;
            if (g != cur) {
                if (cur >= 0) atomicAdd(&energy[cur], sum);
                cur = g; sum = 0.0f;
            }
            sum += e_lds[r];
        }
        if (cur >= 0) atomicAdd(&energy[cur], sum);
    }
}

// ---------------------------------------------------------------------------
extern "C" void kernel_launch(void* const* d_in, const int* in_sizes, int n_in,
                              void* d_out, int out_size, void* d_ws, size_t ws_size,
                              hipStream_t stream)
{
    const int*   atype = (const int*)  d_in[0];
    const float* pos   = (const float*)d_in[1];
    const int*   ei    = (const int*)  d_in[2];
    const int*   batch = (const int*)  d_in[3];
    const float* emb   = (const float*)d_in[4];
    const float* fw1   = (const float*)d_in[5];
    const float* fb1   = (const float*)d_in[6];
    const float* fw2   = (const float*)d_in[7];
    const float* fb2   = (const float*)d_in[8];
    const float* lin1w = (const float*)d_in[9];
    const float* lin2w = (const float*)d_in[10];
    const float* lin2b = (const float*)d_in[11];
    const float* blkw  = (const float*)d_in[12];
    const float* blkb  = (const float*)d_in[13];
    const float* ow1   = (const float*)d_in[14];
    const float* ob1   = (const float*)d_in[15];
    const float* ow2   = (const float*)d_in[16];
    const float* ob2   = (const float*)d_in[17];

    const int Nn = in_sizes[0];
    const int E  = in_sizes[2] / 2;
    float* energy = (float*)d_out;

    // workspace layout
    char* w = (char*)d_ws;
    int*   cnt  = (int*)w;                              // 256 B region
    float* x    = (float*)(w + 256);                    // N*H
    float* hbuf = x + (size_t)Nn * H;                   // N*H
    float* agg  = hbuf + (size_t)Nn * H;                // N*H
    int*   asrc = (int*)(agg + (size_t)Nn * H);         // E
    int*   adst = asrc + E;                             // E
    float* ad   = (float*)(adst + E);                   // E

    hipMemsetAsync(cnt, 0, 256, stream);
    hipMemsetAsync(energy, 0, (size_t)out_size * sizeof(float), stream);

    // x = emb[atom_types]
    {
        int total = (Nn * H) / 4;
        init_x_kernel<<<(total + 255) / 256, 256, 0, stream>>>(atype, emb, x, Nn);
    }
    // edge compaction
    edge_prep_kernel<<<(E + 255) / 256, 256, 0, stream>>>(pos, ei, E, cnt, asrc, adst, ad);

    const int gemmGrid = (Nn + 63) / 64;
    for (int i = 0; i < 2; ++i) {
        const float* fw1i = fw1 + (size_t)i * RBF * H;
        const float* fb1i = fb1 + (size_t)i * H;
        const float* fw2i = fw2 + (size_t)i * H * H;
        const float* fb2i = fb2 + (size_t)i * H;
        const float* l1w  = lin1w + (size_t)i * H * H;
        const float* l2w  = lin2w + (size_t)i * H * H;
        const float* l2b  = lin2b + (size_t)i * H;
        const float* bw   = blkw + (size_t)i * H * H;
        const float* bb   = blkb + (size_t)i * H;

        // h = x @ lin1 (no bias)
        gemm128_kernel<<<gemmGrid, 256, 0, stream>>>(x, l1w, nullptr, nullptr, hbuf, Nn, 0);
        // agg = 0
        hipMemsetAsync(agg, 0, (size_t)Nn * H * sizeof(float), stream);
        // scatter messages over active edges
        edge_filter_kernel<<<1024, 256, 0, stream>>>(cnt, asrc, adst, ad,
                                                     fw1i, fb1i, fw2i, fb2i, hbuf, agg);
        // h = tanh(agg @ lin2 + b)
        gemm128_kernel<<<gemmGrid, 256, 0, stream>>>(agg, l2w, l2b, nullptr, hbuf, Nn, 1);
        // x = x + h @ blk_w + blk_b
        gemm128_kernel<<<gemmGrid, 256, 0, stream>>>(hbuf, bw, bb, x, x, Nn, 0);
    }

    // output head (fused energy reduction)
    out_head_kernel<<<gemmGrid, 256, 0, stream>>>(x, batch, ow1, ob1, ow2, ob2, energy, Nn);
}

// Round 3
// 466.392 us; speedup vs baseline: 1.9808x; 1.1238x over previous
//
#include <hip/hip_runtime.h>
#include <hip/hip_bf16.h>
#include <math.h>

#define H 128
#define RBF 50
#define CUTF 5.0f

// ---------------------------------------------------------------------------
// x[n][h] = emb[atom_types[n]][h]
__global__ __launch_bounds__(256) void init_x_kernel(
    const int* __restrict__ atype, const float* __restrict__ emb,
    float* __restrict__ x, int Nn)
{
    int idx = blockIdx.x * blockDim.x + threadIdx.x;       // one float4 per thread
    if (idx * 4 >= Nn * H) return;
    int n = idx >> 5;                  // 32 float4 per row (128 floats)
    int c = (idx & 31) * 4;
    const float4 v = *(const float4*)(emb + atype[n] * H + c);
    *(float4*)(x + n * H + c) = v;
}

// ---------------------------------------------------------------------------
// Compact edges with d < CUT (Cenv==0 otherwise -> exact skip).
// 4 edges/thread via int4 loads; ballot-compaction, ONE atomic per wave
// (256 edges) -> ~3k total atomics instead of ~12k contended-with-return.
__global__ __launch_bounds__(256) void edge_prep_kernel(
    const float* __restrict__ pos, const int* __restrict__ ei, int E,
    int* __restrict__ cnt, int* __restrict__ asrc, int* __restrict__ adst,
    float* __restrict__ ad)
{
    const int lane = threadIdx.x & 63;
    const int gtid = blockIdx.x * blockDim.x + threadIdx.x;
    const int nchunk = (E + 3) >> 2;
    const int c = gtid;                       // one 4-edge chunk per thread
    const bool inrange = (c < nchunk);

    int s[4], t[4];
    float d[4];
    bool act[4] = {false, false, false, false};

    if (inrange) {
        const int e0 = c * 4;
        if (e0 + 3 < E && (E & 3) == 0) {
            const int4 sv = *(const int4*)(ei + e0);
            const int4 tv = *(const int4*)(ei + E + e0);
            s[0] = sv.x; s[1] = sv.y; s[2] = sv.z; s[3] = sv.w;
            t[0] = tv.x; t[1] = tv.y; t[2] = tv.z; t[3] = tv.w;
            #pragma unroll
            for (int j = 0; j < 4; ++j) {
                float dx = pos[3 * s[j]]     - pos[3 * t[j]];
                float dy = pos[3 * s[j] + 1] - pos[3 * t[j] + 1];
                float dz = pos[3 * s[j] + 2] - pos[3 * t[j] + 2];
                d[j] = sqrtf(dx * dx + dy * dy + dz * dz + 1e-12f);
                act[j] = (d[j] < CUTF);
            }
        } else {
            #pragma unroll
            for (int j = 0; j < 4; ++j) {
                int e = e0 + j;
                if (e < E) {
                    s[j] = ei[e]; t[j] = ei[E + e];
                    float dx = pos[3 * s[j]]     - pos[3 * t[j]];
                    float dy = pos[3 * s[j] + 1] - pos[3 * t[j] + 1];
                    float dz = pos[3 * s[j] + 2] - pos[3 * t[j] + 2];
                    d[j] = sqrtf(dx * dx + dy * dy + dz * dz + 1e-12f);
                    act[j] = (d[j] < CUTF);
                }
            }
        }
    }

    // wave-level compaction: 4 ballots, 1 atomic by lane 0
    unsigned long long b[4];
    int wavetot = 0;
    #pragma unroll
    for (int j = 0; j < 4; ++j) {
        b[j] = __ballot(act[j]);
        wavetot += __popcll(b[j]);
    }
    int base = 0;
    if (lane == 0 && wavetot > 0) base = atomicAdd(cnt, wavetot);
    base = __shfl(base, 0, 64);
    const unsigned long long ltmask = ((unsigned long long)1 << lane) - 1;
    #pragma unroll
    for (int j = 0; j < 4; ++j) {
        if (act[j]) {
            int p = base + (int)__popcll(b[j] & ltmask);
            asrc[p] = s[j]; adst[p] = t[j]; ad[p] = d[j];
        }
        base += (int)__popcll(b[j]);
    }
}

// ---------------------------------------------------------------------------
// One wave (64 lanes) per active edge. lane handles channels h0=lane, h1=lane+64.
//   t = tanh(rbf @ fw1 + fb1); W = (t @ fw2 + fb2) * Cenv
//   msg = h[src]*W ; atomicAdd into agg[dst]
__global__ __launch_bounds__(256) void edge_filter_kernel(
    const int* __restrict__ cnt,
    const int* __restrict__ asrc, const int* __restrict__ adst,
    const float* __restrict__ ad,
    const float* __restrict__ fw1, const float* __restrict__ fb1,
    const float* __restrict__ fw2, const float* __restrict__ fb2,
    const float* __restrict__ hbuf, float* __restrict__ agg)
{
    const int lane = threadIdx.x & 63;
    const int wid = (blockIdx.x * blockDim.x + threadIdx.x) >> 6;
    const int nw  = (gridDim.x * blockDim.x) >> 6;
    const int count = *cnt;
    const float step  = CUTF / 49.0f;
    const float coeff = -0.5f / (step * step);
    const int h0 = lane, h1 = lane + 64;
    const float b1_0 = fb1[h0], b1_1 = fb1[h1];
    const float b2_0 = fb2[h0], b2_1 = fb2[h1];

    for (int i = wid; i < count; i += nw) {
        int s = asrc[i], t = adst[i];
        float d = ad[i];
        float cenv = 0.5f * (cosf(d * (3.14159265358979323846f / CUTF)) + 1.0f);

        // GEMV1: t = tanh(rbf @ fw1 + fb1)  (rbf recomputed per lane, stays in regs)
        float t0 = b1_0, t1 = b1_1;
        #pragma unroll
        for (int r = 0; r < RBF; ++r) {
            float u = d - (float)r * step;
            float rb = expf(coeff * u * u);
            t0 = fmaf(rb, fw1[r * H + h0], t0);
            t1 = fmaf(rb, fw1[r * H + h1], t1);
        }
        t0 = tanhf(t0); t1 = tanhf(t1);

        // GEMV2: W = t @ fw2 + fb2 via shuffle broadcast of t across the wave
        float w0 = b2_0, w1v = b2_1;
        #pragma unroll 8
        for (int k = 0; k < 64; ++k) {
            float bb = __shfl(t0, k, 64);
            w0  = fmaf(bb, fw2[k * H + h0], w0);
            w1v = fmaf(bb, fw2[k * H + h1], w1v);
        }
        #pragma unroll 8
        for (int k = 0; k < 64; ++k) {
            float bb = __shfl(t1, k, 64);
            w0  = fmaf(bb, fw2[(64 + k) * H + h0], w0);
            w1v = fmaf(bb, fw2[(64 + k) * H + h1], w1v);
        }
        w0 *= cenv; w1v *= cenv;

        float m0 = hbuf[s * H + h0] * w0;
        float m1 = hbuf[s * H + h1] * w1v;
        atomicAdd(&agg[t * H + h0], m0);
        atomicAdd(&agg[t * H + h1], m1);
    }
}

// ---------------------------------------------------------------------------
// C[M,128] = A[M,128] @ W[128,128] (+bias) (tanh?) (+resid)
// BM=64, BK=32, 256 threads, microtile 4 rows x (4+4) cols.
__global__ __launch_bounds__(256) void gemm128_kernel(
    const float* __restrict__ A, const float* __restrict__ W,
    const float* __restrict__ bias, const float* __restrict__ resid,
    float* __restrict__ C, int M, int act_tanh)
{
    __shared__ float As[64][33];    // padded to kill bank conflicts
    __shared__ float Ws[32][128];

    const int tid = threadIdx.x;
    const int m0 = blockIdx.x * 64;
    const int r0 = (tid >> 4) * 4;         // 0..60
    const int c0 = (tid & 15) * 4;         // 0..60 ; cols {c0..c0+3, c0+64..c0+67}

    float acc[4][8];
    #pragma unroll
    for (int j = 0; j < 4; ++j)
        #pragma unroll
        for (int c = 0; c < 8; ++c) acc[j][c] = 0.0f;

    for (int kc = 0; kc < 128; kc += 32) {
        // stage A chunk (64 x 32)
        {
            int r = tid >> 3;              // 0..31
            int kk = (tid & 7) * 4;
            #pragma unroll
            for (int p = 0; p < 2; ++p) {
                int row = r + p * 32;
                float4 v = make_float4(0.f, 0.f, 0.f, 0.f);
                if (m0 + row < M) v = *(const float4*)(A + (size_t)(m0 + row) * H + kc + kk);
                As[row][kk] = v.x; As[row][kk + 1] = v.y;
                As[row][kk + 2] = v.z; As[row][kk + 3] = v.w;
            }
        }
        // stage W chunk (32 x 128)
        {
            int wr = tid >> 5;             // 0..7
            int wc = (tid & 31) * 4;
            #pragma unroll
            for (int p = 0; p < 4; ++p) {
                int row = wr + p * 8;
                *(float4*)&Ws[row][wc] = *(const float4*)(W + (size_t)(kc + row) * H + wc);
            }
        }
        __syncthreads();
        #pragma unroll
        for (int k = 0; k < 32; ++k) {
            float a_[4];
            #pragma unroll
            for (int j = 0; j < 4; ++j) a_[j] = As[r0 + j][k];
            float4 wlo = *(float4*)&Ws[k][c0];
            float4 whi = *(float4*)&Ws[k][c0 + 64];
            float w_[8] = {wlo.x, wlo.y, wlo.z, wlo.w, whi.x, whi.y, whi.z, whi.w};
            #pragma unroll
            for (int j = 0; j < 4; ++j)
                #pragma unroll
                for (int c = 0; c < 8; ++c)
                    acc[j][c] = fmaf(a_[j], w_[c], acc[j][c]);
        }
        __syncthreads();
    }

    // epilogue
    #pragma unroll
    for (int j = 0; j < 4; ++j) {
        int row = m0 + r0 + j;
        if (row >= M) continue;
        #pragma unroll
        for (int hh = 0; hh < 2; ++hh) {
            int cb = c0 + hh * 64;
            float v0 = acc[j][hh * 4 + 0], v1 = acc[j][hh * 4 + 1];
            float v2 = acc[j][hh * 4 + 2], v3 = acc[j][hh * 4 + 3];
            if (bias) {
                v0 += bias[cb]; v1 += bias[cb + 1]; v2 += bias[cb + 2]; v3 += bias[cb + 3];
            }
            if (act_tanh) {
                v0 = tanhf(v0); v1 = tanhf(v1); v2 = tanhf(v2); v3 = tanhf(v3);
            }
            if (resid) {
                const float4 rv = *(const float4*)(resid + (size_t)row * H + cb);
                v0 += rv.x; v1 += rv.y; v2 += rv.z; v3 += rv.w;
            }
            float4 out = make_float4(v0, v1, v2, v3);
            *(float4*)(C + (size_t)row * H + cb) = out;
        }
    }
}

// ---------------------------------------------------------------------------
// Output head, GEMM-tiled + fused energy reduction.
__global__ __launch_bounds__(256) void out_head_kernel(
    const float* __restrict__ x, const int* __restrict__ batch,
    const float* __restrict__ w1, const float* __restrict__ b1,
    const float* __restrict__ w2, const float* __restrict__ b2,
    float* __restrict__ energy, int Nn)
{
    __shared__ float As[64][33];
    __shared__ float Ws[32][68];
    __shared__ float e_lds[64];
    __shared__ int   gid_lds[64];

    const int tid = threadIdx.x;
    const int m0 = blockIdx.x * 64;
    const int r0 = (tid >> 4) * 4;         // 0..60
    const int c0 = (tid & 15) * 4;         // 0..60

    float acc[4][4];
    #pragma unroll
    for (int j = 0; j < 4; ++j)
        #pragma unroll
        for (int c = 0; c < 4; ++c) acc[j][c] = 0.0f;

    for (int kc = 0; kc < 128; kc += 32) {
        // stage x chunk (64 rows x 32 k)
        {
            int r = tid >> 3;              // 0..31
            int kk = (tid & 7) * 4;
            #pragma unroll
            for (int p = 0; p < 2; ++p) {
                int row = r + p * 32;
                float4 v = make_float4(0.f, 0.f, 0.f, 0.f);
                if (m0 + row < Nn) v = *(const float4*)(x + (size_t)(m0 + row) * H + kc + kk);
                As[row][kk] = v.x; As[row][kk + 1] = v.y;
                As[row][kk + 2] = v.z; As[row][kk + 3] = v.w;
            }
        }
        // stage w1 chunk (32 k x 64 cols)
        {
            int wr = tid >> 4;             // 0..15
            int wc = (tid & 15) * 4;       // 0..60
            #pragma unroll
            for (int p = 0; p < 2; ++p) {
                int row = wr + p * 16;
                *(float4*)&Ws[row][wc] = *(const float4*)(w1 + (size_t)(kc + row) * 64 + wc);
            }
        }
        __syncthreads();
        #pragma unroll
        for (int k = 0; k < 32; ++k) {
            float a_[4];
            #pragma unroll
            for (int j = 0; j < 4; ++j) a_[j] = As[r0 + j][k];
            float4 wv = *(float4*)&Ws[k][c0];
            float w_[4] = {wv.x, wv.y, wv.z, wv.w};
            #pragma unroll
            for (int j = 0; j < 4; ++j)
                #pragma unroll
                for (int c = 0; c < 4; ++c)
                    acc[j][c] = fmaf(a_[j], w_[c], acc[j][c]);
        }
        __syncthreads();
    }

    // epilogue: e_partial[j] = sum_c tanh(acc+b1)*w2  over this thread's 4 cols
    const float4 b1v = *(const float4*)(b1 + c0);
    const float4 w2v = *(const float4*)(w2 + c0);
    float ep[4];
    #pragma unroll
    for (int j = 0; j < 4; ++j) {
        float v0 = tanhf(acc[j][0] + b1v.x);
        float v1 = tanhf(acc[j][1] + b1v.y);
        float v2 = tanhf(acc[j][2] + b1v.z);
        float v3 = tanhf(acc[j][3] + b1v.w);
        ep[j] = v0 * w2v.x + v1 * w2v.y + v2 * w2v.z + v3 * w2v.w;
    }
    #pragma unroll
    for (int off = 1; off < 16; off <<= 1) {
        #pragma unroll
        for (int j = 0; j < 4; ++j) ep[j] += __shfl_xor(ep[j], off, 64);
    }
    if ((tid & 15) == 0) {
        const float b2v = b2[0];
        #pragma unroll
        for (int j = 0; j < 4; ++j) {
            int row = r0 + j;
            e_lds[row] = ep[j] + b2v;
        }
    }
    if (tid < 64) {
        int row = m0 + tid;
        gid_lds[tid] = (row < Nn) ? batch[row] : -1;
    }
    __syncthreads();

    // segmented flush by thread 0 (batch sorted: ~1-2 distinct gids per block)
    if (tid == 0) {
        int cur = -1; float sum = 0.0f;
        for (int r = 0; r < 64; ++r) {
            int g = gid_lds[r];
            if (g < 0) continue;
            if (g != cur) {
                if (cur >= 0) atomicAdd(&energy[cur], sum);
                cur = g; sum = 0.0f;
            }
            sum += e_lds[r];
        }
        if (cur >= 0) atomicAdd(&energy[cur], sum);
    }
}

// ---------------------------------------------------------------------------
extern "C" void kernel_launch(void* const* d_in, const int* in_sizes, int n_in,
                              void* d_out, int out_size, void* d_ws, size_t ws_size,
                              hipStream_t stream)
{
    const int*   atype = (const int*)  d_in[0];
    const float* pos   = (const float*)d_in[1];
    const int*   ei    = (const int*)  d_in[2];
    const int*   batch = (const int*)  d_in[3];
    const float* emb   = (const float*)d_in[4];
    const float* fw1   = (const float*)d_in[5];
    const float* fb1   = (const float*)d_in[6];
    const float* fw2   = (const float*)d_in[7];
    const float* fb2   = (const float*)d_in[8];
    const float* lin1w = (const float*)d_in[9];
    const float* lin2w = (const float*)d_in[10];
    const float* lin2b = (const float*)d_in[11];
    const float* blkw  = (const float*)d_in[12];
    const float* blkb  = (const float*)d_in[13];
    const float* ow1   = (const float*)d_in[14];
    const float* ob1   = (const float*)d_in[15];
    const float* ow2   = (const float*)d_in[16];
    const float* ob2   = (const float*)d_in[17];

    const int Nn = in_sizes[0];
    const int E  = in_sizes[2] / 2;
    float* energy = (float*)d_out;

    // workspace layout
    char* w = (char*)d_ws;
    int*   cnt  = (int*)w;                              // 256 B region
    float* x    = (float*)(w + 256);                    // N*H
    float* hbuf = x + (size_t)Nn * H;                   // N*H
    float* agg  = hbuf + (size_t)Nn * H;                // N*H
    int*   asrc = (int*)(agg + (size_t)Nn * H);         // E
    int*   adst = asrc + E;                             // E
    float* ad   = (float*)(adst + E);                   // E

    hipMemsetAsync(cnt, 0, 256, stream);
    hipMemsetAsync(energy, 0, (size_t)out_size * sizeof(float), stream);

    // x = emb[atom_types]
    {
        int total = (Nn * H) / 4;
        init_x_kernel<<<(total + 255) / 256, 256, 0, stream>>>(atype, emb, x, Nn);
    }
    // edge compaction: one 4-edge chunk per thread
    {
        int nchunk = (E + 3) / 4;
        edge_prep_kernel<<<(nchunk + 255) / 256, 256, 0, stream>>>(pos, ei, E, cnt, asrc, adst, ad);
    }

    const int gemmGrid = (Nn + 63) / 64;
    for (int i = 0; i < 2; ++i) {
        const float* fw1i = fw1 + (size_t)i * RBF * H;
        const float* fb1i = fb1 + (size_t)i * H;
        const float* fw2i = fw2 + (size_t)i * H * H;
        const float* fb2i = fb2 + (size_t)i * H;
        const float* l1w  = lin1w + (size_t)i * H * H;
        const float* l2w  = lin2w + (size_t)i * H * H;
        const float* l2b  = lin2b + (size_t)i * H;
        const float* bw   = blkw + (size_t)i * H * H;
        const float* bb   = blkb + (size_t)i * H;

        // h = x @ lin1 (no bias)
        gemm128_kernel<<<gemmGrid, 256, 0, stream>>>(x, l1w, nullptr, nullptr, hbuf, Nn, 0);
        // agg = 0
        hipMemsetAsync(agg, 0, (size_t)Nn * H * sizeof(float), stream);
        // scatter messages over active edges
        edge_filter_kernel<<<1024, 256, 0, stream>>>(cnt, asrc, adst, ad,
                                                     fw1i, fb1i, fw2i, fb2i, hbuf, agg);
        // h = tanh(agg @ lin2 + b)
        gemm128_kernel<<<gemmGrid, 256, 0, stream>>>(agg, l2w, l2b, nullptr, hbuf, Nn, 1);
        // x = x + h @ blk_w + blk_b
        gemm128_kernel<<<gemmGrid, 256, 0, stream>>>(hbuf, bw, bb, x, x, Nn, 0);
    }

    // output head (fused energy reduction)
    out_head_kernel<<<gemmGrid, 256, 0, stream>>>(x, batch, ow1, ob1, ow2, ob2, energy, Nn);
}

// Round 4
// 423.668 us; speedup vs baseline: 2.1806x; 1.1008x over previous
//
#include <hip/hip_runtime.h>
#include <hip/hip_bf16.h>
#include <math.h>

#define H 128
#define RBF 50
#define CUTF 5.0f
#define PIF 3.14159265358979323846f

// ---------------------------------------------------------------------------
// x[n][h] = emb[atom_types[n]][h]
__global__ __launch_bounds__(256) void init_x_kernel(
    const int* __restrict__ atype, const float* __restrict__ emb,
    float* __restrict__ x, int Nn)
{
    int idx = blockIdx.x * blockDim.x + threadIdx.x;       // one float4 per thread
    if (idx * 4 >= Nn * H) return;
    int n = idx >> 5;                  // 32 float4 per row (128 floats)
    int c = (idx & 31) * 4;
    const float4 v = *(const float4*)(emb + atype[n] * H + c);
    *(float4*)(x + n * H + c) = v;
}

// ---------------------------------------------------------------------------
// Compact edges with d < CUT (Cenv==0 otherwise -> exact skip).
// Also flags src/dst atoms of active edges.
__global__ __launch_bounds__(256) void edge_prep_kernel(
    const float* __restrict__ pos, const int* __restrict__ ei, int E,
    int* __restrict__ cnt, int* __restrict__ asrc, int* __restrict__ adst,
    float* __restrict__ ad, int* __restrict__ is_src, int* __restrict__ is_dst)
{
    const int lane = threadIdx.x & 63;
    const int gtid = blockIdx.x * blockDim.x + threadIdx.x;
    const int nchunk = (E + 3) >> 2;
    const bool inrange = (gtid < nchunk);

    int s[4], t[4];
    float d[4];
    bool act[4] = {false, false, false, false};

    if (inrange) {
        const int e0 = gtid * 4;
        if (e0 + 3 < E && (E & 3) == 0) {
            const int4 sv = *(const int4*)(ei + e0);
            const int4 tv = *(const int4*)(ei + E + e0);
            s[0] = sv.x; s[1] = sv.y; s[2] = sv.z; s[3] = sv.w;
            t[0] = tv.x; t[1] = tv.y; t[2] = tv.z; t[3] = tv.w;
            #pragma unroll
            for (int j = 0; j < 4; ++j) {
                float dx = pos[3 * s[j]]     - pos[3 * t[j]];
                float dy = pos[3 * s[j] + 1] - pos[3 * t[j] + 1];
                float dz = pos[3 * s[j] + 2] - pos[3 * t[j] + 2];
                d[j] = sqrtf(dx * dx + dy * dy + dz * dz + 1e-12f);
                act[j] = (d[j] < CUTF);
            }
        } else {
            #pragma unroll
            for (int j = 0; j < 4; ++j) {
                int e = e0 + j;
                if (e < E) {
                    s[j] = ei[e]; t[j] = ei[E + e];
                    float dx = pos[3 * s[j]]     - pos[3 * t[j]];
                    float dy = pos[3 * s[j] + 1] - pos[3 * t[j] + 1];
                    float dz = pos[3 * s[j] + 2] - pos[3 * t[j] + 2];
                    d[j] = sqrtf(dx * dx + dy * dy + dz * dz + 1e-12f);
                    act[j] = (d[j] < CUTF);
                }
            }
        }
    }

    unsigned long long b[4];
    int wavetot = 0;
    #pragma unroll
    for (int j = 0; j < 4; ++j) {
        b[j] = __ballot(act[j]);
        wavetot += __popcll(b[j]);
    }
    int base = 0;
    if (lane == 0 && wavetot > 0) base = atomicAdd(cnt, wavetot);
    base = __shfl(base, 0, 64);
    const unsigned long long ltmask = ((unsigned long long)1 << lane) - 1;
    #pragma unroll
    for (int j = 0; j < 4; ++j) {
        if (act[j]) {
            int p = base + (int)__popcll(b[j] & ltmask);
            asrc[p] = s[j]; adst[p] = t[j]; ad[p] = d[j];
            is_src[s[j]] = 1; is_dst[t[j]] = 1;
        }
        base += (int)__popcll(b[j]);
    }
}

// ---------------------------------------------------------------------------
// Ballot-compact atoms into src/dst/nondst lists.
__global__ __launch_bounds__(256) void compact_atoms_kernel(
    const int* __restrict__ is_src, const int* __restrict__ is_dst, int Nn,
    int* __restrict__ cnt4,
    int* __restrict__ src_list, int* __restrict__ dst_list, int* __restrict__ nondst_list)
{
    int n = blockIdx.x * 256 + threadIdx.x;
    int lane = threadIdx.x & 63;
    bool vs = false, vd = false, vn = false;
    if (n < Nn) { vs = is_src[n] != 0; vd = is_dst[n] != 0; vn = !vd; }
    const unsigned long long ltm = ((unsigned long long)1 << lane) - 1;
    {
        unsigned long long b = __ballot(vs);
        int tot = __popcll(b); int base = 0;
        if (lane == 0 && tot) base = atomicAdd(cnt4 + 1, tot);
        base = __shfl(base, 0, 64);
        if (vs) src_list[base + (int)__popcll(b & ltm)] = n;
    }
    {
        unsigned long long b = __ballot(vd);
        int tot = __popcll(b); int base = 0;
        if (lane == 0 && tot) base = atomicAdd(cnt4 + 2, tot);
        base = __shfl(base, 0, 64);
        if (vd) dst_list[base + (int)__popcll(b & ltm)] = n;
    }
    {
        unsigned long long b = __ballot(vn);
        int tot = __popcll(b); int base = 0;
        if (lane == 0 && tot) base = atomicAdd(cnt4 + 3, tot);
        base = __shfl(base, 0, 64);
        if (vn) nondst_list[base + (int)__popcll(b & ltm)] = n;
    }
}

// ---------------------------------------------------------------------------
// cvec[i] = tanh(lin2_b_i) @ blk_w_i + blk_b_i   (per interaction block)
__global__ void cvec_kernel(const float* __restrict__ lin2b,
                            const float* __restrict__ blkw,
                            const float* __restrict__ blkb,
                            float* __restrict__ cvec)
{
    int i = blockIdx.x;
    int c = threadIdx.x;          // 128 threads
    __shared__ float tl[H];
    tl[c] = tanhf(lin2b[i * H + c]);
    __syncthreads();
    float acc = blkb[i * H + c];
    for (int k = 0; k < H; ++k)
        acc = fmaf(tl[k], blkw[(size_t)i * H * H + (size_t)k * H + c], acc);
    cvec[i * H + c] = acc;
}

// ---------------------------------------------------------------------------
// Row-gathered GEMM: C[rows[i]] = [tanh](A[rows[i]] @ W [+ bias]) [+ resid[rows[i]]]
// 64-row tiles, block-stride over tiles; count from device.
__global__ __launch_bounds__(256) void gemm_rows_kernel(
    const float* __restrict__ A, const float* __restrict__ W,
    const float* __restrict__ bias, const float* __restrict__ resid,
    float* __restrict__ C, const int* __restrict__ rows,
    const int* __restrict__ cntp, int act_tanh)
{
    __shared__ float As[64][36];      // padded; float4-readable over k
    __shared__ float Ws[32][128];
    __shared__ int rlist[64];

    const int tid = threadIdx.x;
    const int cnt = *cntp;
    const int r0 = (tid >> 4) * 4;
    const int c0 = (tid & 15) * 4;

    for (int tile = blockIdx.x; tile * 64 < cnt; tile += gridDim.x) {
        __syncthreads();
        if (tid < 64) {
            int idx = tile * 64 + tid;
            rlist[tid] = (idx < cnt) ? rows[idx] : -1;
        }
        __syncthreads();

        float acc[4][8];
        #pragma unroll
        for (int j = 0; j < 4; ++j)
            #pragma unroll
            for (int c = 0; c < 8; ++c) acc[j][c] = 0.f;

        for (int kc = 0; kc < H; kc += 32) {
            {
                int lr = tid >> 3;
                int kk = (tid & 7) * 4;
                #pragma unroll
                for (int p = 0; p < 2; ++p) {
                    int row = lr + p * 32;
                    int r = rlist[row];
                    float4 v = make_float4(0.f, 0.f, 0.f, 0.f);
                    if (r >= 0) v = *(const float4*)(A + (size_t)r * H + kc + kk);
                    *(float4*)&As[row][kk] = v;
                }
            }
            {
                int wr = tid >> 5;
                int wc = (tid & 31) * 4;
                #pragma unroll
                for (int p = 0; p < 4; ++p) {
                    int row = wr + p * 8;
                    *(float4*)&Ws[row][wc] = *(const float4*)(W + (size_t)(kc + row) * H + wc);
                }
            }
            __syncthreads();
            #pragma unroll
            for (int k = 0; k < 32; k += 4) {
                float a_[4][4];
                #pragma unroll
                for (int j = 0; j < 4; ++j)
                    *(float4*)a_[j] = *(const float4*)&As[r0 + j][k];
                #pragma unroll
                for (int kk = 0; kk < 4; ++kk) {
                    float4 wlo = *(const float4*)&Ws[k + kk][c0];
                    float4 whi = *(const float4*)&Ws[k + kk][c0 + 64];
                    float w_[8] = {wlo.x, wlo.y, wlo.z, wlo.w, whi.x, whi.y, whi.z, whi.w};
                    #pragma unroll
                    for (int j = 0; j < 4; ++j)
                        #pragma unroll
                        for (int c = 0; c < 8; ++c)
                            acc[j][c] = fmaf(a_[j][kk], w_[c], acc[j][c]);
                }
            }
            __syncthreads();
        }
        #pragma unroll
        for (int j = 0; j < 4; ++j) {
            int r = rlist[r0 + j];
            if (r < 0) continue;
            #pragma unroll
            for (int hh = 0; hh < 2; ++hh) {
                int cb = c0 + hh * 64;
                float v0 = acc[j][hh * 4 + 0], v1 = acc[j][hh * 4 + 1];
                float v2 = acc[j][hh * 4 + 2], v3 = acc[j][hh * 4 + 3];
                if (bias) { v0 += bias[cb]; v1 += bias[cb + 1]; v2 += bias[cb + 2]; v3 += bias[cb + 3]; }
                if (act_tanh) { v0 = tanhf(v0); v1 = tanhf(v1); v2 = tanhf(v2); v3 = tanhf(v3); }
                if (resid) {
                    float4 rv = *(const float4*)(resid + (size_t)r * H + cb);
                    v0 += rv.x; v1 += rv.y; v2 += rv.z; v3 += rv.w;
                }
                *(float4*)(C + (size_t)r * H + cb) = make_float4(v0, v1, v2, v3);
            }
        }
    }
}

// ---------------------------------------------------------------------------
// zero rows of a [*,H] matrix listed in rows[0..cnt)
__global__ __launch_bounds__(256) void zero_rows_kernel(
    float* __restrict__ dst, const int* __restrict__ rows, const int* __restrict__ cntp)
{
    int cnt = *cntp;
    int total = cnt * 32;
    for (int idx = blockIdx.x * 256 + threadIdx.x; idx < total; idx += gridDim.x * 256) {
        int row = idx >> 5, c = (idx & 31) << 2;
        int r = rows[row];
        *(float4*)(dst + (size_t)r * H + c) = make_float4(0.f, 0.f, 0.f, 0.f);
    }
}

// x[rows[i]] += cvec  (the constant no-incoming-edge block update)
__global__ __launch_bounds__(256) void add_cvec_kernel(
    float* __restrict__ x, const int* __restrict__ rows, const int* __restrict__ cntp,
    const float* __restrict__ cvec)
{
    int cnt = *cntp;
    int total = cnt * 32;
    for (int idx = blockIdx.x * 256 + threadIdx.x; idx < total; idx += gridDim.x * 256) {
        int row = idx >> 5, c = (idx & 31) << 2;
        int r = rows[row];
        float4 v = *(const float4*)(x + (size_t)r * H + c);
        float4 cv = *(const float4*)(cvec + c);
        v.x += cv.x; v.y += cv.y; v.z += cv.z; v.w += cv.w;
        *(float4*)(x + (size_t)r * H + c) = v;
    }
}

// ---------------------------------------------------------------------------
// Fused edge filter as tiled GEMM: 64 edges per tile.
//   rbf (LDS) -> t = tanh(rbf@fw1+fb1) (LDS) -> W = (t@fw2+fb2)*cenv
//   epilogue: msg = W * h[src]; atomicAdd agg[dst]
__global__ __launch_bounds__(256) void edge_gemm_kernel(
    const int* __restrict__ cnt,
    const int* __restrict__ asrc, const int* __restrict__ adst,
    const float* __restrict__ ad,
    const float* __restrict__ fw1, const float* __restrict__ fb1,
    const float* __restrict__ fw2, const float* __restrict__ fb2,
    const float* __restrict__ hbuf, float* __restrict__ agg)
{
    __shared__ float t_l[64][132];        // 33.0 KB
    __shared__ float st[32 * 128];        // 16 KB staging: fw1 chunks (25x128) / fw2 (32x128)
    __shared__ float rbf_l[64 * RBF];     // 12.5 KB
    __shared__ float d_l[64], cenv_l[64];
    __shared__ int src_l[64], dst_l[64];

    const int tid = threadIdx.x;
    const int count = *cnt;
    const int r0 = (tid >> 4) * 4;
    const int c0 = (tid & 15) * 4;
    const float step = CUTF / 49.0f;
    const float coeff = -0.5f / (step * step);

    const float4 fb1lo = *(const float4*)(fb1 + c0);
    const float4 fb1hi = *(const float4*)(fb1 + c0 + 64);
    const float4 fb2lo = *(const float4*)(fb2 + c0);
    const float4 fb2hi = *(const float4*)(fb2 + c0 + 64);

    for (int tile = blockIdx.x; tile * 64 < count; tile += gridDim.x) {
        const int base = tile * 64;
        const int nedge = min(64, count - base);
        __syncthreads();
        if (tid < 64) {
            float d = 1e9f; int s = 0, t = 0;
            if (tid < nedge) { d = ad[base + tid]; s = asrc[base + tid]; t = adst[base + tid]; }
            d_l[tid] = d; src_l[tid] = s; dst_l[tid] = t;
            cenv_l[tid] = (d < CUTF) ? 0.5f * (cosf(d * (PIF / CUTF)) + 1.0f) : 0.0f;
        }
        __syncthreads();
        for (int i = tid; i < 64 * RBF; i += 256) {
            int e = i / RBF;
            int r = i - e * RBF;
            float u = d_l[e] - (float)r * step;
            rbf_l[i] = expf(coeff * u * u);      // dummy d=1e9 -> exp(-huge) = 0
        }

        // phase 2: t = tanh(rbf @ fw1 + fb1), fw1 staged in 25-row chunks
        float acc[4][8];
        #pragma unroll
        for (int j = 0; j < 4; ++j)
            #pragma unroll
            for (int c = 0; c < 8; ++c) acc[j][c] = 0.f;

        for (int kb = 0; kb < RBF; kb += 25) {
            __syncthreads();   // rbf writes visible / prev chunk consumed
            for (int i = tid; i < 25 * 32; i += 256) {
                int r = i >> 5, c = (i & 31) * 4;
                *(float4*)&st[r * 128 + c] = *(const float4*)(fw1 + (size_t)(kb + r) * H + c);
            }
            __syncthreads();
            for (int k = 0; k < 25; ++k) {
                float a_[4];
                #pragma unroll
                for (int j = 0; j < 4; ++j) a_[j] = rbf_l[(r0 + j) * RBF + kb + k];
                float4 wlo = *(const float4*)&st[k * 128 + c0];
                float4 whi = *(const float4*)&st[k * 128 + c0 + 64];
                float w_[8] = {wlo.x, wlo.y, wlo.z, wlo.w, whi.x, whi.y, whi.z, whi.w};
                #pragma unroll
                for (int j = 0; j < 4; ++j)
                    #pragma unroll
                    for (int c = 0; c < 8; ++c)
                        acc[j][c] = fmaf(a_[j], w_[c], acc[j][c]);
            }
        }
        #pragma unroll
        for (int j = 0; j < 4; ++j) {
            float4 lo, hi;
            lo.x = tanhf(acc[j][0] + fb1lo.x); lo.y = tanhf(acc[j][1] + fb1lo.y);
            lo.z = tanhf(acc[j][2] + fb1lo.z); lo.w = tanhf(acc[j][3] + fb1lo.w);
            hi.x = tanhf(acc[j][4] + fb1hi.x); hi.y = tanhf(acc[j][5] + fb1hi.y);
            hi.z = tanhf(acc[j][6] + fb1hi.z); hi.w = tanhf(acc[j][7] + fb1hi.w);
            *(float4*)&t_l[r0 + j][c0] = lo;
            *(float4*)&t_l[r0 + j][c0 + 64] = hi;
        }

        // phase 3: W = t @ fw2
        float acc3[4][8];
        #pragma unroll
        for (int j = 0; j < 4; ++j)
            #pragma unroll
            for (int c = 0; c < 8; ++c) acc3[j][c] = 0.f;

        for (int kc = 0; kc < H; kc += 32) {
            __syncthreads();  // t_l writes visible; prev st usage done
            {
                int wr = tid >> 5;
                int wc = (tid & 31) * 4;
                #pragma unroll
                for (int p = 0; p < 4; ++p) {
                    int row = wr + p * 8;
                    *(float4*)&st[row * 128 + wc] = *(const float4*)(fw2 + (size_t)(kc + row) * H + wc);
                }
            }
            __syncthreads();
            #pragma unroll
            for (int k = 0; k < 32; k += 4) {
                float a_[4][4];
                #pragma unroll
                for (int j = 0; j < 4; ++j)
                    *(float4*)a_[j] = *(const float4*)&t_l[r0 + j][kc + k];
                #pragma unroll
                for (int kk = 0; kk < 4; ++kk) {
                    float4 wlo = *(const float4*)&st[(k + kk) * 128 + c0];
                    float4 whi = *(const float4*)&st[(k + kk) * 128 + c0 + 64];
                    float w_[8] = {wlo.x, wlo.y, wlo.z, wlo.w, whi.x, whi.y, whi.z, whi.w};
                    #pragma unroll
                    for (int j = 0; j < 4; ++j)
                        #pragma unroll
                        for (int c = 0; c < 8; ++c)
                            acc3[j][c] = fmaf(a_[j][kk], w_[c], acc3[j][c]);
                }
            }
        }

        // epilogue: scale, gather h[src], scatter-atomic agg[dst]
        #pragma unroll
        for (int j = 0; j < 4; ++j) {
            int row = r0 + j;
            if (row >= nedge) continue;
            float ce = cenv_l[row];
            int s = src_l[row], t = dst_l[row];
            const float4 hlo = *(const float4*)(hbuf + (size_t)s * H + c0);
            const float4 hhi = *(const float4*)(hbuf + (size_t)s * H + c0 + 64);
            float m0 = (acc3[j][0] + fb2lo.x) * ce * hlo.x;
            float m1 = (acc3[j][1] + fb2lo.y) * ce * hlo.y;
            float m2 = (acc3[j][2] + fb2lo.z) * ce * hlo.z;
            float m3 = (acc3[j][3] + fb2lo.w) * ce * hlo.w;
            float m4 = (acc3[j][4] + fb2hi.x) * ce * hhi.x;
            float m5 = (acc3[j][5] + fb2hi.y) * ce * hhi.y;
            float m6 = (acc3[j][6] + fb2hi.z) * ce * hhi.z;
            float m7 = (acc3[j][7] + fb2hi.w) * ce * hhi.w;
            float* ag = agg + (size_t)t * H;
            atomicAdd(ag + c0 + 0, m0); atomicAdd(ag + c0 + 1, m1);
            atomicAdd(ag + c0 + 2, m2); atomicAdd(ag + c0 + 3, m3);
            atomicAdd(ag + c0 + 64, m4); atomicAdd(ag + c0 + 65, m5);
            atomicAdd(ag + c0 + 66, m6); atomicAdd(ag + c0 + 67, m7);
        }
    }
}

// ---------------------------------------------------------------------------
// Output head, GEMM-tiled + fused energy reduction.
__global__ __launch_bounds__(256) void out_head_kernel(
    const float* __restrict__ x, const int* __restrict__ batch,
    const float* __restrict__ w1, const float* __restrict__ b1,
    const float* __restrict__ w2, const float* __restrict__ b2,
    float* __restrict__ energy, int Nn)
{
    __shared__ float As[64][33];
    __shared__ float Ws[32][68];
    __shared__ float e_lds[64];
    __shared__ int   gid_lds[64];

    const int tid = threadIdx.x;
    const int m0 = blockIdx.x * 64;
    const int r0 = (tid >> 4) * 4;
    const int c0 = (tid & 15) * 4;

    float acc[4][4];
    #pragma unroll
    for (int j = 0; j < 4; ++j)
        #pragma unroll
        for (int c = 0; c < 4; ++c) acc[j][c] = 0.0f;

    for (int kc = 0; kc < 128; kc += 32) {
        {
            int r = tid >> 3;
            int kk = (tid & 7) * 4;
            #pragma unroll
            for (int p = 0; p < 2; ++p) {
                int row = r + p * 32;
                float4 v = make_float4(0.f, 0.f, 0.f, 0.f);
                if (m0 + row < Nn) v = *(const float4*)(x + (size_t)(m0 + row) * H + kc + kk);
                As[row][kk] = v.x; As[row][kk + 1] = v.y;
                As[row][kk + 2] = v.z; As[row][kk + 3] = v.w;
            }
        }
        {
            int wr = tid >> 4;
            int wc = (tid & 15) * 4;
            #pragma unroll
            for (int p = 0; p < 2; ++p) {
                int row = wr + p * 16;
                *(float4*)&Ws[row][wc] = *(const float4*)(w1 + (size_t)(kc + row) * 64 + wc);
            }
        }
        __syncthreads();
        #pragma unroll
        for (int k = 0; k < 32; ++k) {
            float a_[4];
            #pragma unroll
            for (int j = 0; j < 4; ++j) a_[j] = As[r0 + j][k];
            float4 wv = *(float4*)&Ws[k][c0];
            float w_[4] = {wv.x, wv.y, wv.z, wv.w};
            #pragma unroll
            for (int j = 0; j < 4; ++j)
                #pragma unroll
                for (int c = 0; c < 4; ++c)
                    acc[j][c] = fmaf(a_[j], w_[c], acc[j][c]);
        }
        __syncthreads();
    }

    const float4 b1v = *(const float4*)(b1 + c0);
    const float4 w2v = *(const float4*)(w2 + c0);
    float ep[4];
    #pragma unroll
    for (int j = 0; j < 4; ++j) {
        float v0 = tanhf(acc[j][0] + b1v.x);
        float v1 = tanhf(acc[j][1] + b1v.y);
        float v2 = tanhf(acc[j][2] + b1v.z);
        float v3 = tanhf(acc[j][3] + b1v.w);
        ep[j] = v0 * w2v.x + v1 * w2v.y + v2 * w2v.z + v3 * w2v.w;
    }
    #pragma unroll
    for (int off = 1; off < 16; off <<= 1) {
        #pragma unroll
        for (int j = 0; j < 4; ++j) ep[j] += __shfl_xor(ep[j], off, 64);
    }
    if ((tid & 15) == 0) {
        const float b2v = b2[0];
        #pragma unroll
        for (int j = 0; j < 4; ++j) e_lds[r0 + j] = ep[j] + b2v;
    }
    if (tid < 64) {
        int row = m0 + tid;
        gid_lds[tid] = (row < Nn) ? batch[row] : -1;
    }
    __syncthreads();

    if (tid == 0) {
        int cur = -1; float sum = 0.0f;
        for (int r = 0; r < 64; ++r) {
            int g = gid_lds[r];
            if (g < 0) continue;
            if (g != cur) {
                if (cur >= 0) atomicAdd(&energy[cur], sum);
                cur = g; sum = 0.0f;
            }
            sum += e_lds[r];
        }
        if (cur >= 0) atomicAdd(&energy[cur], sum);
    }
}

// ---------------------------------------------------------------------------
extern "C" void kernel_launch(void* const* d_in, const int* in_sizes, int n_in,
                              void* d_out, int out_size, void* d_ws, size_t ws_size,
                              hipStream_t stream)
{
    const int*   atype = (const int*)  d_in[0];
    const float* pos   = (const float*)d_in[1];
    const int*   ei    = (const int*)  d_in[2];
    const int*   batch = (const int*)  d_in[3];
    const float* emb   = (const float*)d_in[4];
    const float* fw1   = (const float*)d_in[5];
    const float* fb1   = (const float*)d_in[6];
    const float* fw2   = (const float*)d_in[7];
    const float* fb2   = (const float*)d_in[8];
    const float* lin1w = (const float*)d_in[9];
    const float* lin2w = (const float*)d_in[10];
    const float* lin2b = (const float*)d_in[11];
    const float* blkw  = (const float*)d_in[12];
    const float* blkb  = (const float*)d_in[13];
    const float* ow1   = (const float*)d_in[14];
    const float* ob1   = (const float*)d_in[15];
    const float* ow2   = (const float*)d_in[16];
    const float* ob2   = (const float*)d_in[17];

    const int Nn = in_sizes[0];
    const int E  = in_sizes[2] / 2;
    float* energy = (float*)d_out;

    // workspace layout
    char* w = (char*)d_ws;
    int*   cnt  = (int*)w;                   // [0]=edges [1]=src [2]=dst [3]=nondst
    float* x    = (float*)(w + 256);                    // N*H
    float* hbuf = x + (size_t)Nn * H;                   // N*H
    float* agg  = hbuf + (size_t)Nn * H;                // N*H
    int*   asrc = (int*)(agg + (size_t)Nn * H);         // E
    int*   adst = asrc + E;                             // E
    float* ad   = (float*)(adst + E);                   // E
    int*   is_src = (int*)(ad + E);                     // N
    int*   is_dst = is_src + Nn;                        // N
    int*   src_list = is_dst + Nn;                      // N
    int*   dst_list = src_list + Nn;                    // N
    int*   nondst_list = dst_list + Nn;                 // N
    float* cvec = (float*)(nondst_list + Nn);           // 2*H

    hipMemsetAsync(cnt, 0, 256, stream);
    hipMemsetAsync(energy, 0, (size_t)out_size * sizeof(float), stream);
    hipMemsetAsync(is_src, 0, 2 * (size_t)Nn * sizeof(int), stream);   // is_src + is_dst

    // x = emb[atom_types]
    {
        int total = (Nn * H) / 4;
        init_x_kernel<<<(total + 255) / 256, 256, 0, stream>>>(atype, emb, x, Nn);
    }
    // edge compaction + atom flags
    {
        int nchunk = (E + 3) / 4;
        edge_prep_kernel<<<(nchunk + 255) / 256, 256, 0, stream>>>(
            pos, ei, E, cnt, asrc, adst, ad, is_src, is_dst);
    }
    compact_atoms_kernel<<<(Nn + 255) / 256, 256, 0, stream>>>(
        is_src, is_dst, Nn, cnt, src_list, dst_list, nondst_list);
    cvec_kernel<<<2, H, 0, stream>>>(lin2b, blkw, blkb, cvec);

    for (int i = 0; i < 2; ++i) {
        const float* fw1i = fw1 + (size_t)i * RBF * H;
        const float* fb1i = fb1 + (size_t)i * H;
        const float* fw2i = fw2 + (size_t)i * H * H;
        const float* fb2i = fb2 + (size_t)i * H;
        const float* l1w  = lin1w + (size_t)i * H * H;
        const float* l2w  = lin2w + (size_t)i * H * H;
        const float* l2b  = lin2b + (size_t)i * H;
        const float* bw   = blkw + (size_t)i * H * H;
        const float* bb   = blkb + (size_t)i * H;

        // h[src] = x[src] @ lin1
        gemm_rows_kernel<<<256, 256, 0, stream>>>(x, l1w, nullptr, nullptr, hbuf,
                                                  src_list, cnt + 1, 0);
        // agg[dst] = 0
        zero_rows_kernel<<<512, 256, 0, stream>>>(agg, dst_list, cnt + 2);
        // edge filter GEMM + scatter
        edge_gemm_kernel<<<512, 256, 0, stream>>>(cnt, asrc, adst, ad,
                                                  fw1i, fb1i, fw2i, fb2i, hbuf, agg);
        // h2[dst] = tanh(agg[dst] @ lin2 + b)
        gemm_rows_kernel<<<256, 256, 0, stream>>>(agg, l2w, l2b, nullptr, hbuf,
                                                  dst_list, cnt + 2, 1);
        // x[dst] += h2[dst] @ blk_w + blk_b
        gemm_rows_kernel<<<256, 256, 0, stream>>>(hbuf, bw, bb, x, x,
                                                  dst_list, cnt + 2, 0);
        // x[nondst] += cvec_i
        add_cvec_kernel<<<512, 256, 0, stream>>>(x, nondst_list, cnt + 3, cvec + i * H);
    }

    // output head (fused energy reduction)
    out_head_kernel<<<(Nn + 63) / 64, 256, 0, stream>>>(x, batch, ow1, ob1, ow2, ob2, energy, Nn);
}

// Round 5
// 325.907 us; speedup vs baseline: 2.8347x; 1.3000x over previous
//
#include <hip/hip_runtime.h>
#include <hip/hip_bf16.h>
#include <math.h>

#define H 128
#define RBF 50
#define CUTF 5.0f
#define PIF 3.14159265358979323846f
#define QT 1024                       // filter table intervals (QT+1 knots)

// ---------------------------------------------------------------------------
__global__ __launch_bounds__(256) void init_x_kernel(
    const int* __restrict__ atype, const float* __restrict__ emb,
    float* __restrict__ x, int Nn)
{
    int idx = blockIdx.x * blockDim.x + threadIdx.x;
    if (idx * 4 >= Nn * H) return;
    int n = idx >> 5;
    int c = (idx & 31) * 4;
    const float4 v = *(const float4*)(emb + atype[n] * H + c);
    *(float4*)(x + n * H + c) = v;
}

// ---------------------------------------------------------------------------
// Compact edges with d < CUT; flag src/dst atoms.
__global__ __launch_bounds__(256) void edge_prep_kernel(
    const float* __restrict__ pos, const int* __restrict__ ei, int E,
    int* __restrict__ cnt, int* __restrict__ asrc, int* __restrict__ adst,
    float* __restrict__ ad, int* __restrict__ is_src, int* __restrict__ is_dst)
{
    const int lane = threadIdx.x & 63;
    const int gtid = blockIdx.x * blockDim.x + threadIdx.x;
    const int nchunk = (E + 3) >> 2;
    const bool inrange = (gtid < nchunk);

    int s[4], t[4];
    float d[4];
    bool act[4] = {false, false, false, false};

    if (inrange) {
        const int e0 = gtid * 4;
        if (e0 + 3 < E && (E & 3) == 0) {
            const int4 sv = *(const int4*)(ei + e0);
            const int4 tv = *(const int4*)(ei + E + e0);
            s[0] = sv.x; s[1] = sv.y; s[2] = sv.z; s[3] = sv.w;
            t[0] = tv.x; t[1] = tv.y; t[2] = tv.z; t[3] = tv.w;
            #pragma unroll
            for (int j = 0; j < 4; ++j) {
                float dx = pos[3 * s[j]]     - pos[3 * t[j]];
                float dy = pos[3 * s[j] + 1] - pos[3 * t[j] + 1];
                float dz = pos[3 * s[j] + 2] - pos[3 * t[j] + 2];
                d[j] = sqrtf(dx * dx + dy * dy + dz * dz + 1e-12f);
                act[j] = (d[j] < CUTF);
            }
        } else {
            #pragma unroll
            for (int j = 0; j < 4; ++j) {
                int e = e0 + j;
                if (e < E) {
                    s[j] = ei[e]; t[j] = ei[E + e];
                    float dx = pos[3 * s[j]]     - pos[3 * t[j]];
                    float dy = pos[3 * s[j] + 1] - pos[3 * t[j] + 1];
                    float dz = pos[3 * s[j] + 2] - pos[3 * t[j] + 2];
                    d[j] = sqrtf(dx * dx + dy * dy + dz * dz + 1e-12f);
                    act[j] = (d[j] < CUTF);
                }
            }
        }
    }

    unsigned long long b[4];
    int wavetot = 0;
    #pragma unroll
    for (int j = 0; j < 4; ++j) {
        b[j] = __ballot(act[j]);
        wavetot += __popcll(b[j]);
    }
    int base = 0;
    if (lane == 0 && wavetot > 0) base = atomicAdd(cnt, wavetot);
    base = __shfl(base, 0, 64);
    const unsigned long long ltmask = ((unsigned long long)1 << lane) - 1;
    #pragma unroll
    for (int j = 0; j < 4; ++j) {
        if (act[j]) {
            int p = base + (int)__popcll(b[j] & ltmask);
            asrc[p] = s[j]; adst[p] = t[j]; ad[p] = d[j];
            is_src[s[j]] = 1; is_dst[t[j]] = 1;
        }
        base += (int)__popcll(b[j]);
    }
}

// ---------------------------------------------------------------------------
__global__ __launch_bounds__(256) void compact_atoms_kernel(
    const int* __restrict__ is_src, const int* __restrict__ is_dst, int Nn,
    int* __restrict__ cnt4,
    int* __restrict__ src_list, int* __restrict__ dst_list, int* __restrict__ nondst_list)
{
    int n = blockIdx.x * 256 + threadIdx.x;
    int lane = threadIdx.x & 63;
    bool vs = false, vd = false, vn = false;
    if (n < Nn) { vs = is_src[n] != 0; vd = is_dst[n] != 0; vn = !vd; }
    const unsigned long long ltm = ((unsigned long long)1 << lane) - 1;
    {
        unsigned long long b = __ballot(vs);
        int tot = __popcll(b); int base = 0;
        if (lane == 0 && tot) base = atomicAdd(cnt4 + 1, tot);
        base = __shfl(base, 0, 64);
        if (vs) src_list[base + (int)__popcll(b & ltm)] = n;
    }
    {
        unsigned long long b = __ballot(vd);
        int tot = __popcll(b); int base = 0;
        if (lane == 0 && tot) base = atomicAdd(cnt4 + 2, tot);
        base = __shfl(base, 0, 64);
        if (vd) dst_list[base + (int)__popcll(b & ltm)] = n;
    }
    {
        unsigned long long b = __ballot(vn);
        int tot = __popcll(b); int base = 0;
        if (lane == 0 && tot) base = atomicAdd(cnt4 + 3, tot);
        base = __shfl(base, 0, 64);
        if (vn) nondst_list[base + (int)__popcll(b & ltm)] = n;
    }
}

// ---------------------------------------------------------------------------
// cvec[i] = tanh(lin2_b_i) @ blk_w_i + blk_b_i
__global__ void cvec_kernel(const float* __restrict__ lin2b,
                            const float* __restrict__ blkw,
                            const float* __restrict__ blkb,
                            float* __restrict__ cvec)
{
    int i = blockIdx.x;
    int c = threadIdx.x;
    __shared__ float tl[H];
    tl[c] = tanhf(lin2b[i * H + c]);
    __syncthreads();
    float acc = blkb[i * H + c];
    for (int k = 0; k < H; ++k)
        acc = fmaf(tl[k], blkw[(size_t)i * H * H + (size_t)k * H + c], acc);
    cvec[i * H + c] = acc;
}

// ---------------------------------------------------------------------------
// Filter table: tab[blk][q][h] = ((tanh(rbf(d_q)@fw1+fb1))@fw2 + fb2) * cenv(d_q)
// d_q = q * CUT/QT, q = 0..QT. One wave per (blk, knot).
__global__ __launch_bounds__(256) void filter_table_kernel(
    const float* __restrict__ fw1, const float* __restrict__ fb1,
    const float* __restrict__ fw2, const float* __restrict__ fb2,
    float* __restrict__ tab)
{
    const int lane = threadIdx.x & 63;
    const int wid = (blockIdx.x * blockDim.x + threadIdx.x) >> 6;
    const int total = 2 * (QT + 1);
    if (wid >= total) return;
    const int blk = wid / (QT + 1);
    const int q = wid - blk * (QT + 1);
    const float d = (float)q * (CUTF / (float)QT);

    const float* f1 = fw1 + (size_t)blk * RBF * H;
    const float* f2 = fw2 + (size_t)blk * H * H;
    const float step  = CUTF / 49.0f;
    const float coeff = -0.5f / (step * step);
    const int h0 = lane, h1 = lane + 64;

    float cenv = (d < CUTF) ? 0.5f * (cosf(d * (PIF / CUTF)) + 1.0f) : 0.0f;

    float t0 = fb1[blk * H + h0], t1 = fb1[blk * H + h1];
    #pragma unroll
    for (int r = 0; r < RBF; ++r) {
        float u = d - (float)r * step;
        float rb = expf(coeff * u * u);
        t0 = fmaf(rb, f1[r * H + h0], t0);
        t1 = fmaf(rb, f1[r * H + h1], t1);
    }
    t0 = tanhf(t0); t1 = tanhf(t1);

    float w0 = fb2[blk * H + h0], w1v = fb2[blk * H + h1];
    #pragma unroll 8
    for (int k = 0; k < 64; ++k) {
        float bb = __shfl(t0, k, 64);
        w0  = fmaf(bb, f2[k * H + h0], w0);
        w1v = fmaf(bb, f2[k * H + h1], w1v);
    }
    #pragma unroll 8
    for (int k = 0; k < 64; ++k) {
        float bb = __shfl(t1, k, 64);
        w0  = fmaf(bb, f2[(64 + k) * H + h0], w0);
        w1v = fmaf(bb, f2[(64 + k) * H + h1], w1v);
    }
    float* row = tab + ((size_t)blk * (QT + 1) + q) * H;
    row[h0] = w0 * cenv;
    row[h1] = w1v * cenv;
}

// ---------------------------------------------------------------------------
// Per-edge scatter: W = lerp(table, d); msg = W * h[src]; atomicAdd agg[dst].
__global__ __launch_bounds__(256) void edge_scatter_kernel(
    const int* __restrict__ cnt,
    const int* __restrict__ asrc, const int* __restrict__ adst,
    const float* __restrict__ ad, const float* __restrict__ tab,
    const float* __restrict__ hbuf, float* __restrict__ agg)
{
    const int lane = threadIdx.x & 63;
    const int wid = (blockIdx.x * blockDim.x + threadIdx.x) >> 6;
    const int nw  = (gridDim.x * blockDim.x) >> 6;
    const int count = *cnt;
    const float scale = (float)QT / CUTF;

    for (int i = wid; i < count; i += nw) {
        int s = asrc[i], t = adst[i];
        float p = ad[i] * scale;
        int i0 = (int)p;
        if (i0 > QT - 1) i0 = QT - 1;
        float f = p - (float)i0;
        const float* r0 = tab + (size_t)i0 * H;
        float wl = fmaf(f, r0[H + lane] - r0[lane], r0[lane]);
        float wh = fmaf(f, r0[H + 64 + lane] - r0[64 + lane], r0[64 + lane]);
        float m0 = hbuf[(size_t)s * H + lane] * wl;
        float m1 = hbuf[(size_t)s * H + 64 + lane] * wh;
        atomicAdd(agg + (size_t)t * H + lane, m0);
        atomicAdd(agg + (size_t)t * H + 64 + lane, m1);
    }
}

// ---------------------------------------------------------------------------
// Row-gathered GEMM, 32-row tiles: C[rows[i]] = [tanh](A[rows[i]]@W [+bias])
__global__ __launch_bounds__(256) void gemm_rows_kernel(
    const float* __restrict__ A, const float* __restrict__ W,
    const float* __restrict__ bias, float* __restrict__ C,
    const int* __restrict__ rows, const int* __restrict__ cntp, int act_tanh)
{
    __shared__ float As[32][36];
    __shared__ float Ws[32][128];
    __shared__ int rlist[32];

    const int tid = threadIdx.x;
    const int cnt = *cntp;
    const int r0 = (tid >> 4) * 2;
    const int c0 = (tid & 15) * 4;

    for (int tile = blockIdx.x; tile * 32 < cnt; tile += gridDim.x) {
        __syncthreads();
        if (tid < 32) {
            int idx = tile * 32 + tid;
            rlist[tid] = (idx < cnt) ? rows[idx] : -1;
        }
        __syncthreads();

        float acc[2][8];
        #pragma unroll
        for (int j = 0; j < 2; ++j)
            #pragma unroll
            for (int c = 0; c < 8; ++c) acc[j][c] = 0.f;

        for (int kc = 0; kc < H; kc += 32) {
            {
                int lr = tid >> 3;
                int kk = (tid & 7) * 4;
                int r = rlist[lr];
                float4 v = make_float4(0.f, 0.f, 0.f, 0.f);
                if (r >= 0) v = *(const float4*)(A + (size_t)r * H + kc + kk);
                *(float4*)&As[lr][kk] = v;
            }
            {
                int wr = tid >> 5;
                int wc = (tid & 31) * 4;
                #pragma unroll
                for (int p = 0; p < 4; ++p) {
                    int row = wr + p * 8;
                    *(float4*)&Ws[row][wc] = *(const float4*)(W + (size_t)(kc + row) * H + wc);
                }
            }
            __syncthreads();
            #pragma unroll
            for (int k = 0; k < 32; k += 4) {
                float a_[2][4];
                #pragma unroll
                for (int j = 0; j < 2; ++j)
                    *(float4*)a_[j] = *(const float4*)&As[r0 + j][k];
                #pragma unroll
                for (int kk = 0; kk < 4; ++kk) {
                    float4 wlo = *(const float4*)&Ws[k + kk][c0];
                    float4 whi = *(const float4*)&Ws[k + kk][c0 + 64];
                    float w_[8] = {wlo.x, wlo.y, wlo.z, wlo.w, whi.x, whi.y, whi.z, whi.w};
                    #pragma unroll
                    for (int j = 0; j < 2; ++j)
                        #pragma unroll
                        for (int c = 0; c < 8; ++c)
                            acc[j][c] = fmaf(a_[j][kk], w_[c], acc[j][c]);
                }
            }
            __syncthreads();
        }
        #pragma unroll
        for (int j = 0; j < 2; ++j) {
            int r = rlist[r0 + j];
            if (r < 0) continue;
            #pragma unroll
            for (int hh = 0; hh < 2; ++hh) {
                int cb = c0 + hh * 64;
                float v0 = acc[j][hh * 4 + 0], v1 = acc[j][hh * 4 + 1];
                float v2 = acc[j][hh * 4 + 2], v3 = acc[j][hh * 4 + 3];
                if (bias) { v0 += bias[cb]; v1 += bias[cb + 1]; v2 += bias[cb + 2]; v3 += bias[cb + 3]; }
                if (act_tanh) { v0 = tanhf(v0); v1 = tanhf(v1); v2 = tanhf(v2); v3 = tanhf(v3); }
                *(float4*)(C + (size_t)r * H + cb) = make_float4(v0, v1, v2, v3);
            }
        }
    }
}

// ---------------------------------------------------------------------------
// Fused dst update: x[r] += tanh(agg[r]@l2w + l2b)@bw + bb   (32-row tiles)
__global__ __launch_bounds__(256) void dst_update_kernel(
    const float* __restrict__ agg, const float* __restrict__ l2w,
    const float* __restrict__ l2b, const float* __restrict__ bw,
    const float* __restrict__ bb, float* __restrict__ x,
    const int* __restrict__ rows, const int* __restrict__ cntp)
{
    __shared__ float As[32][36];
    __shared__ float Ws[32][128];
    __shared__ float Tl[32][132];
    __shared__ int rlist[32];

    const int tid = threadIdx.x;
    const int cnt = *cntp;
    const int r0 = (tid >> 4) * 2;
    const int c0 = (tid & 15) * 4;

    for (int tile = blockIdx.x; tile * 32 < cnt; tile += gridDim.x) {
        __syncthreads();
        if (tid < 32) {
            int idx = tile * 32 + tid;
            rlist[tid] = (idx < cnt) ? rows[idx] : -1;
        }
        __syncthreads();

        // phase A: T = tanh(agg @ l2w + l2b)
        float acc[2][8];
        #pragma unroll
        for (int j = 0; j < 2; ++j)
            #pragma unroll
            for (int c = 0; c < 8; ++c) acc[j][c] = 0.f;

        for (int kc = 0; kc < H; kc += 32) {
            {
                int lr = tid >> 3;
                int kk = (tid & 7) * 4;
                int r = rlist[lr];
                float4 v = make_float4(0.f, 0.f, 0.f, 0.f);
                if (r >= 0) v = *(const float4*)(agg + (size_t)r * H + kc + kk);
                *(float4*)&As[lr][kk] = v;
            }
            {
                int wr = tid >> 5;
                int wc = (tid & 31) * 4;
                #pragma unroll
                for (int p = 0; p < 4; ++p) {
                    int row = wr + p * 8;
                    *(float4*)&Ws[row][wc] = *(const float4*)(l2w + (size_t)(kc + row) * H + wc);
                }
            }
            __syncthreads();
            #pragma unroll
            for (int k = 0; k < 32; k += 4) {
                float a_[2][4];
                #pragma unroll
                for (int j = 0; j < 2; ++j)
                    *(float4*)a_[j] = *(const float4*)&As[r0 + j][k];
                #pragma unroll
                for (int kk = 0; kk < 4; ++kk) {
                    float4 wlo = *(const float4*)&Ws[k + kk][c0];
                    float4 whi = *(const float4*)&Ws[k + kk][c0 + 64];
                    float w_[8] = {wlo.x, wlo.y, wlo.z, wlo.w, whi.x, whi.y, whi.z, whi.w};
                    #pragma unroll
                    for (int j = 0; j < 2; ++j)
                        #pragma unroll
                        for (int c = 0; c < 8; ++c)
                            acc[j][c] = fmaf(a_[j][kk], w_[c], acc[j][c]);
                }
            }
            __syncthreads();
        }
        #pragma unroll
        for (int j = 0; j < 2; ++j) {
            float4 lo, hi;
            lo.x = tanhf(acc[j][0] + l2b[c0]);     lo.y = tanhf(acc[j][1] + l2b[c0 + 1]);
            lo.z = tanhf(acc[j][2] + l2b[c0 + 2]); lo.w = tanhf(acc[j][3] + l2b[c0 + 3]);
            hi.x = tanhf(acc[j][4] + l2b[c0 + 64]); hi.y = tanhf(acc[j][5] + l2b[c0 + 65]);
            hi.z = tanhf(acc[j][6] + l2b[c0 + 66]); hi.w = tanhf(acc[j][7] + l2b[c0 + 67]);
            *(float4*)&Tl[r0 + j][c0] = lo;
            *(float4*)&Tl[r0 + j][c0 + 64] = hi;
        }

        // phase B: U = T @ bw + bb ; x[r] += U
        float acc2[2][8];
        #pragma unroll
        for (int j = 0; j < 2; ++j)
            #pragma unroll
            for (int c = 0; c < 8; ++c) acc2[j][c] = 0.f;

        for (int kc = 0; kc < H; kc += 32) {
            __syncthreads();   // Tl writes visible; prev Ws reads done
            {
                int wr = tid >> 5;
                int wc = (tid & 31) * 4;
                #pragma unroll
                for (int p = 0; p < 4; ++p) {
                    int row = wr + p * 8;
                    *(float4*)&Ws[row][wc] = *(const float4*)(bw + (size_t)(kc + row) * H + wc);
                }
            }
            __syncthreads();
            #pragma unroll
            for (int k = 0; k < 32; k += 4) {
                float a_[2][4];
                #pragma unroll
                for (int j = 0; j < 2; ++j)
                    *(float4*)a_[j] = *(const float4*)&Tl[r0 + j][kc + k];
                #pragma unroll
                for (int kk = 0; kk < 4; ++kk) {
                    float4 wlo = *(const float4*)&Ws[k + kk][c0];
                    float4 whi = *(const float4*)&Ws[k + kk][c0 + 64];
                    float w_[8] = {wlo.x, wlo.y, wlo.z, wlo.w, whi.x, whi.y, whi.z, whi.w};
                    #pragma unroll
                    for (int j = 0; j < 2; ++j)
                        #pragma unroll
                        for (int c = 0; c < 8; ++c)
                            acc2[j][c] = fmaf(a_[j][kk], w_[c], acc2[j][c]);
                }
            }
        }
        #pragma unroll
        for (int j = 0; j < 2; ++j) {
            int r = rlist[r0 + j];
            if (r < 0) continue;
            #pragma unroll
            for (int hh = 0; hh < 2; ++hh) {
                int cb = c0 + hh * 64;
                float4 xv = *(const float4*)(x + (size_t)r * H + cb);
                xv.x += acc2[j][hh * 4 + 0] + bb[cb];
                xv.y += acc2[j][hh * 4 + 1] + bb[cb + 1];
                xv.z += acc2[j][hh * 4 + 2] + bb[cb + 2];
                xv.w += acc2[j][hh * 4 + 3] + bb[cb + 3];
                *(float4*)(x + (size_t)r * H + cb) = xv;
            }
        }
    }
}

// ---------------------------------------------------------------------------
__global__ __launch_bounds__(256) void zero_rows_kernel(
    float* __restrict__ dst, const int* __restrict__ rows, const int* __restrict__ cntp)
{
    int cnt = *cntp;
    int total = cnt * 32;
    for (int idx = blockIdx.x * 256 + threadIdx.x; idx < total; idx += gridDim.x * 256) {
        int row = idx >> 5, c = (idx & 31) << 2;
        int r = rows[row];
        *(float4*)(dst + (size_t)r * H + c) = make_float4(0.f, 0.f, 0.f, 0.f);
    }
}

__global__ __launch_bounds__(256) void add_cvec_kernel(
    float* __restrict__ x, const int* __restrict__ rows, const int* __restrict__ cntp,
    const float* __restrict__ cvec)
{
    int cnt = *cntp;
    int total = cnt * 32;
    for (int idx = blockIdx.x * 256 + threadIdx.x; idx < total; idx += gridDim.x * 256) {
        int row = idx >> 5, c = (idx & 31) << 2;
        int r = rows[row];
        float4 v = *(const float4*)(x + (size_t)r * H + c);
        float4 cv = *(const float4*)(cvec + c);
        v.x += cv.x; v.y += cv.y; v.z += cv.z; v.w += cv.w;
        *(float4*)(x + (size_t)r * H + c) = v;
    }
}

// ---------------------------------------------------------------------------
__global__ __launch_bounds__(256) void out_head_kernel(
    const float* __restrict__ x, const int* __restrict__ batch,
    const float* __restrict__ w1, const float* __restrict__ b1,
    const float* __restrict__ w2, const float* __restrict__ b2,
    float* __restrict__ energy, int Nn)
{
    __shared__ float As[64][33];
    __shared__ float Ws[32][68];
    __shared__ float e_lds[64];
    __shared__ int   gid_lds[64];

    const int tid = threadIdx.x;
    const int m0 = blockIdx.x * 64;
    const int r0 = (tid >> 4) * 4;
    const int c0 = (tid & 15) * 4;

    float acc[4][4];
    #pragma unroll
    for (int j = 0; j < 4; ++j)
        #pragma unroll
        for (int c = 0; c < 4; ++c) acc[j][c] = 0.0f;

    for (int kc = 0; kc < 128; kc += 32) {
        {
            int r = tid >> 3;
            int kk = (tid & 7) * 4;
            #pragma unroll
            for (int p = 0; p < 2; ++p) {
                int row = r + p * 32;
                float4 v = make_float4(0.f, 0.f, 0.f, 0.f);
                if (m0 + row < Nn) v = *(const float4*)(x + (size_t)(m0 + row) * H + kc + kk);
                As[row][kk] = v.x; As[row][kk + 1] = v.y;
                As[row][kk + 2] = v.z; As[row][kk + 3] = v.w;
            }
        }
        {
            int wr = tid >> 4;
            int wc = (tid & 15) * 4;
            #pragma unroll
            for (int p = 0; p < 2; ++p) {
                int row = wr + p * 16;
                *(float4*)&Ws[row][wc] = *(const float4*)(w1 + (size_t)(kc + row) * 64 + wc);
            }
        }
        __syncthreads();
        #pragma unroll
        for (int k = 0; k < 32; ++k) {
            float a_[4];
            #pragma unroll
            for (int j = 0; j < 4; ++j) a_[j] = As[r0 + j][k];
            float4 wv = *(float4*)&Ws[k][c0];
            float w_[4] = {wv.x, wv.y, wv.z, wv.w};
            #pragma unroll
            for (int j = 0; j < 4; ++j)
                #pragma unroll
                for (int c = 0; c < 4; ++c)
                    acc[j][c] = fmaf(a_[j], w_[c], acc[j][c]);
        }
        __syncthreads();
    }

    const float4 b1v = *(const float4*)(b1 + c0);
    const float4 w2v = *(const float4*)(w2 + c0);
    float ep[4];
    #pragma unroll
    for (int j = 0; j < 4; ++j) {
        float v0 = tanhf(acc[j][0] + b1v.x);
        float v1 = tanhf(acc[j][1] + b1v.y);
        float v2 = tanhf(acc[j][2] + b1v.z);
        float v3 = tanhf(acc[j][3] + b1v.w);
        ep[j] = v0 * w2v.x + v1 * w2v.y + v2 * w2v.z + v3 * w2v.w;
    }
    #pragma unroll
    for (int off = 1; off < 16; off <<= 1) {
        #pragma unroll
        for (int j = 0; j < 4; ++j) ep[j] += __shfl_xor(ep[j], off, 64);
    }
    if ((tid & 15) == 0) {
        const float b2v = b2[0];
        #pragma unroll
        for (int j = 0; j < 4; ++j) e_lds[r0 + j] = ep[j] + b2v;
    }
    if (tid < 64) {
        int row = m0 + tid;
        gid_lds[tid] = (row < Nn) ? batch[row] : -1;
    }
    __syncthreads();

    if (tid == 0) {
        int cur = -1; float sum = 0.0f;
        for (int r = 0; r < 64; ++r) {
            int g = gid_lds[r];
            if (g < 0) continue;
            if (g != cur) {
                if (cur >= 0) atomicAdd(&energy[cur], sum);
                cur = g; sum = 0.0f;
            }
            sum += e_lds[r];
        }
        if (cur >= 0) atomicAdd(&energy[cur], sum);
    }
}

// ---------------------------------------------------------------------------
extern "C" void kernel_launch(void* const* d_in, const int* in_sizes, int n_in,
                              void* d_out, int out_size, void* d_ws, size_t ws_size,
                              hipStream_t stream)
{
    const int*   atype = (const int*)  d_in[0];
    const float* pos   = (const float*)d_in[1];
    const int*   ei    = (const int*)  d_in[2];
    const int*   batch = (const int*)  d_in[3];
    const float* emb   = (const float*)d_in[4];
    const float* fw1   = (const float*)d_in[5];
    const float* fb1   = (const float*)d_in[6];
    const float* fw2   = (const float*)d_in[7];
    const float* fb2   = (const float*)d_in[8];
    const float* lin1w = (const float*)d_in[9];
    const float* lin2w = (const float*)d_in[10];
    const float* lin2b = (const float*)d_in[11];
    const float* blkw  = (const float*)d_in[12];
    const float* blkb  = (const float*)d_in[13];
    const float* ow1   = (const float*)d_in[14];
    const float* ob1   = (const float*)d_in[15];
    const float* ow2   = (const float*)d_in[16];
    const float* ob2   = (const float*)d_in[17];

    const int Nn = in_sizes[0];
    const int E  = in_sizes[2] / 2;
    float* energy = (float*)d_out;

    // workspace layout
    char* w = (char*)d_ws;
    int*   cnt  = (int*)w;                   // [0]=edges [1]=src [2]=dst [3]=nondst
    float* x    = (float*)(w + 256);                    // N*H
    float* hbuf = x + (size_t)Nn * H;                   // N*H
    float* agg  = hbuf + (size_t)Nn * H;                // N*H
    int*   asrc = (int*)(agg + (size_t)Nn * H);         // E
    int*   adst = asrc + E;                             // E
    float* ad   = (float*)(adst + E);                   // E
    int*   is_src = (int*)(ad + E);                     // N
    int*   is_dst = is_src + Nn;                        // N
    int*   src_list = is_dst + Nn;                      // N
    int*   dst_list = src_list + Nn;                    // N
    int*   nondst_list = dst_list + Nn;                 // N
    float* cvec = (float*)(nondst_list + Nn);           // 2*H
    float* tab  = cvec + 2 * H;                         // 2*(QT+1)*H

    hipMemsetAsync(cnt, 0, 256, stream);
    hipMemsetAsync(energy, 0, (size_t)out_size * sizeof(float), stream);
    hipMemsetAsync(is_src, 0, 2 * (size_t)Nn * sizeof(int), stream);

    {
        int total = (Nn * H) / 4;
        init_x_kernel<<<(total + 255) / 256, 256, 0, stream>>>(atype, emb, x, Nn);
    }
    {
        int nchunk = (E + 3) / 4;
        edge_prep_kernel<<<(nchunk + 255) / 256, 256, 0, stream>>>(
            pos, ei, E, cnt, asrc, adst, ad, is_src, is_dst);
    }
    compact_atoms_kernel<<<(Nn + 255) / 256, 256, 0, stream>>>(
        is_src, is_dst, Nn, cnt, src_list, dst_list, nondst_list);
    cvec_kernel<<<2, H, 0, stream>>>(lin2b, blkw, blkb, cvec);
    {
        int waves = 2 * (QT + 1);
        filter_table_kernel<<<(waves + 3) / 4, 256, 0, stream>>>(fw1, fb1, fw2, fb2, tab);
    }

    for (int i = 0; i < 2; ++i) {
        const float* l1w  = lin1w + (size_t)i * H * H;
        const float* l2w  = lin2w + (size_t)i * H * H;
        const float* l2b  = lin2b + (size_t)i * H;
        const float* bw   = blkw + (size_t)i * H * H;
        const float* bb   = blkb + (size_t)i * H;
        const float* tabi = tab + (size_t)i * (QT + 1) * H;

        // h[src] = x[src] @ lin1
        gemm_rows_kernel<<<512, 256, 0, stream>>>(x, l1w, nullptr, hbuf,
                                                  src_list, cnt + 1, 0);
        // agg[dst] = 0
        zero_rows_kernel<<<512, 256, 0, stream>>>(agg, dst_list, cnt + 2);
        // per-edge: lerp filter table, gather h, scatter agg
        edge_scatter_kernel<<<1024, 256, 0, stream>>>(cnt, asrc, adst, ad,
                                                      tabi, hbuf, agg);
        // x[dst] += tanh(agg@l2w+l2b)@bw + bb
        dst_update_kernel<<<512, 256, 0, stream>>>(agg, l2w, l2b, bw, bb, x,
                                                   dst_list, cnt + 2);
        // x[nondst] += cvec_i
        add_cvec_kernel<<<512, 256, 0, stream>>>(x, nondst_list, cnt + 3, cvec + i * H);
    }

    out_head_kernel<<<(Nn + 63) / 64, 256, 0, stream>>>(x, batch, ow1, ob1, ow2, ob2, energy, Nn);
}